// Round 2
// baseline (1206.611 us; speedup 1.0000x reference)
//
#include <hip/hip_runtime.h>
#include <hip/hip_bf16.h>

typedef __hip_bfloat16 bf16;
typedef __attribute__((ext_vector_type(8))) short s16x8;   // 8 bf16 (4 VGPRs) MFMA frag
typedef __attribute__((ext_vector_type(4))) float f32x4;   // MFMA accumulator

#define NN 1024      // nodes
#define NE 30720     // edges
#define CS 32
#define CV 8
#define CZ 128
#define INS 28
#define INV 37
#define NRDIM 139    // 28 + 3*37
#define INZ 1664
#define WN 1664      // WEIGHT_NUMEL
#define NL 4

__device__ __forceinline__ float b2f(bf16 x) { return __bfloat162float(x); }
__device__ __forceinline__ bf16 f2b(float x) { return __float2bfloat16(x); }

// ---------------------------------------------------------------------------
// Skinny MFMA GEMM, N=128 fixed (used for ee1 K=1664 fp32-A and eu1 gather).
// Tile M=64 -> grid 480. AF32: A fp32 converted in staging. GATHER: row e =
// [a_b[dst[e]] | a_b[src[e]] | ef_b[e]] (K=384).
// ---------------------------------------------------------------------------
template<int RELU, int AF32, int GATHER>
__global__ __launch_bounds__(256)
void gemm64(const void* __restrict__ Ap, const bf16* __restrict__ Bt,
            const float* __restrict__ bias, bf16* __restrict__ Cp,
            int M, int K,
            const bf16* __restrict__ g_a, const bf16* __restrict__ g_ef,
            const int* __restrict__ g_ei)
{
    __shared__ __align__(16) bf16 la[64 * 40];
    __shared__ __align__(16) bf16 lb[128 * 40];
    const int bm = blockIdx.x * 64;
    const int tid = threadIdx.x;
    const int lane = tid & 63;
    const int wv = tid >> 6;
    const int lr = tid >> 1;
    const int lc = (tid & 1) * 16;
    const int l15 = lane & 15;
    const int quad = lane >> 4;
    f32x4 acc[4][2] = {};
    const bf16* gb = Bt + (size_t)lr * K + lc;
    const bf16*  ga16 = (const bf16*) Ap + (size_t)(bm + lr) * K + lc;
    const float* ga32 = (const float*)Ap + (size_t)(bm + lr) * K + lc;
    int gdst = 0, gsrc = 0, grow = 0;
    if (GATHER && tid < 128) {
        grow = bm + lr;
        gdst = g_ei[grow];
        gsrc = g_ei[NE + grow];
    }
    for (int k0 = 0; k0 < K; k0 += 32) {
        union { bf16 h[16]; float4 q[2]; } pa;
        if (tid < 128) {
            if (AF32) {
                float4 f0 = *(const float4*)(ga32 + k0);
                float4 f1 = *(const float4*)(ga32 + k0 + 4);
                float4 f2 = *(const float4*)(ga32 + k0 + 8);
                float4 f3 = *(const float4*)(ga32 + k0 + 12);
                pa.h[0]=f2b(f0.x); pa.h[1]=f2b(f0.y); pa.h[2]=f2b(f0.z); pa.h[3]=f2b(f0.w);
                pa.h[4]=f2b(f1.x); pa.h[5]=f2b(f1.y); pa.h[6]=f2b(f1.z); pa.h[7]=f2b(f1.w);
                pa.h[8]=f2b(f2.x); pa.h[9]=f2b(f2.y); pa.h[10]=f2b(f2.z); pa.h[11]=f2b(f2.w);
                pa.h[12]=f2b(f3.x); pa.h[13]=f2b(f3.y); pa.h[14]=f2b(f3.z); pa.h[15]=f2b(f3.w);
            } else if (GATHER) {
                int kk = k0 + lc;
                const bf16* src;
                if (kk < 128)      src = g_a  + (size_t)gdst * CZ + kk;
                else if (kk < 256) src = g_a  + (size_t)gsrc * CZ + (kk - 128);
                else               src = g_ef + (size_t)grow * CZ + (kk - 256);
                pa.q[0] = *(const float4*)src;
                pa.q[1] = *(const float4*)(src + 8);
            } else {
                pa.q[0] = *(const float4*)(ga16 + k0);
                pa.q[1] = *(const float4*)(ga16 + k0 + 8);
            }
        }
        float4 b0 = *(const float4*)(gb + k0);
        float4 b1 = *(const float4*)(gb + k0 + 8);
        __syncthreads();
        if (tid < 128) {
            *(float4*)&la[lr * 40 + lc]     = pa.q[0];
            *(float4*)&la[lr * 40 + lc + 8] = pa.q[1];
        }
        *(float4*)&lb[lr * 40 + lc]     = b0;
        *(float4*)&lb[lr * 40 + lc + 8] = b1;
        __syncthreads();
        s16x8 af[4], bfr[2];
#pragma unroll
        for (int mi = 0; mi < 4; mi++)
            af[mi] = *(const s16x8*)&la[(mi * 16 + l15) * 40 + quad * 8];
#pragma unroll
        for (int ni = 0; ni < 2; ni++)
            bfr[ni] = *(const s16x8*)&lb[(wv * 32 + ni * 16 + l15) * 40 + quad * 8];
#pragma unroll
        for (int mi = 0; mi < 4; mi++)
#pragma unroll
            for (int ni = 0; ni < 2; ni++)
                acc[mi][ni] = __builtin_amdgcn_mfma_f32_16x16x32_bf16(af[mi], bfr[ni], acc[mi][ni], 0, 0, 0);
    }
#pragma unroll
    for (int ni = 0; ni < 2; ni++) {
        const int col = wv * 32 + ni * 16 + l15;
        const float bv = bias[col];
#pragma unroll
        for (int mi = 0; mi < 4; mi++) {
            const int row0 = bm + mi * 16 + quad * 4;
#pragma unroll
            for (int r = 0; r < 4; r++) {
                float v = acc[mi][ni][r] + bv;
                if (RELU) v = fmaxf(v, 0.f);
                Cp[(size_t)(row0 + r) * CZ + col] = f2b(v);
            }
        }
    }
}

// ---------------------------------------------------------------------------
// Fused MLP tail: u2 = relu(A@W2+b2); u3 = u2@W3+b3 (+resid); LN -> efb (bf16)
// Block = 64 rows. Used for ee (RESID=0) and eu (RESID=1, resid==efb in/out).
// ---------------------------------------------------------------------------
template<int RESID>
__global__ __launch_bounds__(256)
void mlp2(const bf16* __restrict__ A,
          const bf16* __restrict__ w2t, const float* __restrict__ b2,
          const bf16* __restrict__ w3t, const float* __restrict__ b3,
          const float* __restrict__ g, const float* __restrict__ bb,
          bf16* efb)
{
    __shared__ __align__(16) bf16 s_a[64 * 136];
    __shared__ __align__(16) bf16 s_u[64 * 136];
    __shared__ float s_o[64 * 132];
    const int bm = blockIdx.x * 64;
    const int t = threadIdx.x;
    const int lane = t & 63;
    const int wv = t >> 6;
    const int l15 = lane & 15;
    const int quad = lane >> 4;
    {   // stage A tile 64x128
        int r = t >> 2, c0 = (t & 3) * 32;
        const float4* s4 = (const float4*)(A + (size_t)(bm + r) * CZ + c0);
        float4* d4 = (float4*)&s_a[r * 136 + c0];
        d4[0] = s4[0]; d4[1] = s4[1]; d4[2] = s4[2]; d4[3] = s4[3];
    }
    __syncthreads();
    s16x8 af[4][4];
#pragma unroll
    for (int mi = 0; mi < 4; mi++)
#pragma unroll
        for (int kk = 0; kk < 4; kk++)
            af[mi][kk] = *(const s16x8*)&s_a[(mi * 16 + l15) * 136 + kk * 32 + quad * 8];
    // stage 1: relu(A@W2+b2) -> s_u
#pragma unroll
    for (int s = 0; s < 2; s++) {
        int n = wv * 32 + s * 16 + l15;
        f32x4 acc[4] = {};
#pragma unroll
        for (int kk = 0; kk < 4; kk++) {
            s16x8 bfr = *(const s16x8*)(w2t + (size_t)n * CZ + kk * 32 + quad * 8);
#pragma unroll
            for (int mi = 0; mi < 4; mi++)
                acc[mi] = __builtin_amdgcn_mfma_f32_16x16x32_bf16(af[mi][kk], bfr, acc[mi], 0, 0, 0);
        }
        float bv = b2[n];
#pragma unroll
        for (int mi = 0; mi < 4; mi++)
#pragma unroll
            for (int r = 0; r < 4; r++)
                s_u[(mi * 16 + quad * 4 + r) * 136 + n] = f2b(fmaxf(acc[mi][r] + bv, 0.f));
    }
    __syncthreads();
#pragma unroll
    for (int mi = 0; mi < 4; mi++)
#pragma unroll
        for (int kk = 0; kk < 4; kk++)
            af[mi][kk] = *(const s16x8*)&s_u[(mi * 16 + l15) * 136 + kk * 32 + quad * 8];
    // stage 2: u2@W3+b3 -> s_o (f32)
#pragma unroll
    for (int s = 0; s < 2; s++) {
        int n = wv * 32 + s * 16 + l15;
        f32x4 acc[4] = {};
#pragma unroll
        for (int kk = 0; kk < 4; kk++) {
            s16x8 bfr = *(const s16x8*)(w3t + (size_t)n * CZ + kk * 32 + quad * 8);
#pragma unroll
            for (int mi = 0; mi < 4; mi++)
                acc[mi] = __builtin_amdgcn_mfma_f32_16x16x32_bf16(af[mi][kk], bfr, acc[mi], 0, 0, 0);
        }
        float bv = b3[n];
#pragma unroll
        for (int mi = 0; mi < 4; mi++)
#pragma unroll
            for (int r = 0; r < 4; r++)
                s_o[(mi * 16 + quad * 4 + r) * 132 + n] = acc[mi][r] + bv;
    }
    __syncthreads();
    // LN per row: 4 lanes per row, 32 cols each
    {
        int row = wv * 16 + (lane >> 2);
        int q = lane & 3;
        int col0 = q * 32;
        size_t gbase = (size_t)(bm + row) * CZ;
        float s = 0.f, s2 = 0.f;
        for (int i = 0; i < 32; i++) {
            float x = s_o[row * 132 + col0 + i];
            if (RESID) x += b2f(efb[gbase + col0 + i]);
            s += x; s2 += x * x;
        }
        s  += __shfl_xor(s, 1);  s2 += __shfl_xor(s2, 1);
        s  += __shfl_xor(s, 2);  s2 += __shfl_xor(s2, 2);
        float mean = s * (1.f / 128.f);
        float var  = s2 * (1.f / 128.f) - mean * mean;
        float rstd = rsqrtf(var + 1e-5f);
        for (int i = 0; i < 32; i++) {
            int col = col0 + i;
            float x = s_o[row * 132 + col];
            if (RESID) x += b2f(efb[gbase + col]);
            efb[gbase + col] = f2b((x - mean) * rstd * g[col] + bb[col]);
        }
    }
}

// ---------------------------------------------------------------------------
// Fused fc1 + fc2 + tensor product.  Block = 16 edges (grid 1920).
// Phase 2 streams W2 rows through MFMA and contracts w = h@W2+b2 in registers.
// NO GLOBAL ATOMICS: per-edge TP outputs are written with plain coalesced
// stores to tp_s[e][32] / tp_v[e][24]; a separate CSR-gather kernel does the
// segment-sum (the 1.72M contended atomics were the latency floor: both prior
// versions sat at 140-156us with MfmaUtil<4%, VALU<10%, HBM<2%).
// ---------------------------------------------------------------------------
__global__ __launch_bounds__(256)
void fc2_tp(const bf16* __restrict__ ef,
            const bf16* __restrict__ w1t, const float* __restrict__ b1,
            const bf16* __restrict__ w2t, const float* __restrict__ b2,
            const int* __restrict__ ei, const float* __restrict__ edge_vecs,
            const float* __restrict__ xs, const float* __restrict__ xv,
            float* __restrict__ tp_s, float* __restrict__ tp_v)
{
    __shared__ __align__(16) bf16 s_a[16 * 136];
    __shared__ __align__(16) bf16 s_h[16 * 136];
    __shared__ __align__(16) float s_xsT[32][16];   // xs[dst[e]][i] -> [i][e]
    __shared__ __align__(16) float s_xvT[24][16];   // xv[dst[e]][i*3+x] -> [i*3+x][e]
    __shared__ __align__(16) float s_crT[24][16];   // cross, pre-scaled by 1/sqrt(2)
    __shared__ __align__(16) float s_y4T[8][16];    // dot(xv,shv), pre-scaled by 2/sqrt(3)
    __shared__ float s_shv[16][3];
    __shared__ int s_dst[16];
    __shared__ float s_os[16][32];                  // scalar-output reduce buffer
    __shared__ float s_ov[16][24];                  // vector-output reduce buffer
    const int be = blockIdx.x * 16;
    const int t = threadIdx.x;
    const int lane = t & 63;
    const int wv = t >> 6;
    const int l15 = lane & 15;
    const int quad = lane >> 4;

    if (t < 16) {
        int e = be + t;
        s_dst[t] = ei[e];
        float vx = edge_vecs[e * 3 + 0];
        float vy = edge_vecs[e * 3 + 1];
        float vz = edge_vecs[e * 3 + 2];
        float sc = 1.7320508075688772f / (sqrtf(vx * vx + vy * vy + vz * vz) + 1e-8f);
        s_shv[t][0] = vx * sc; s_shv[t][1] = vy * sc; s_shv[t][2] = vz * sc;
    }
    for (int i = t; i < 512; i += 256) ((float*)s_os)[i] = 0.f;
    for (int i = t; i < 384; i += 256) ((float*)s_ov)[i] = 0.f;
    {   // stage ef tile 16x128
        int r = t >> 4, c0 = (t & 15) * 8;
        *(float4*)&s_a[r * 136 + c0] = *(const float4*)(ef + (size_t)(be + r) * CZ + c0);
    }
    __syncthreads();
    for (int i = t; i < 16 * 32; i += 256) { int e = i & 15, c = i >> 4; s_xsT[c][e] = xs[s_dst[e] * CS + c]; }
    for (int i = t; i < 16 * 24; i += 256) { int e = i & 15, c = i >> 4; s_xvT[c][e] = xv[s_dst[e] * 24 + c]; }
    __syncthreads();
    if (t < 128) {   // y4 + cross from transposed xv, path-constants pre-folded
        int e = t & 15, i = t >> 4;
        float h0 = s_shv[e][0], h1 = s_shv[e][1], h2 = s_shv[e][2];
        float x0 = s_xvT[i * 3 + 0][e], x1 = s_xvT[i * 3 + 1][e], x2 = s_xvT[i * 3 + 2][e];
        s_y4T[i][e] = 1.1547005383792515f * (x0 * h0 + x1 * h1 + x2 * h2);
        s_crT[i * 3 + 0][e] = 0.7071067811865476f * (x1 * h2 - x2 * h1);
        s_crT[i * 3 + 1][e] = 0.7071067811865476f * (x2 * h0 - x0 * h2);
        s_crT[i * 3 + 2][e] = 0.7071067811865476f * (x0 * h1 - x1 * h0);
    }
    // phase 1: h = relu(ef@W1+b1), M=16 N=128 K=128
    {
        s16x8 af1[4];
#pragma unroll
        for (int kk = 0; kk < 4; kk++)
            af1[kk] = *(const s16x8*)&s_a[l15 * 136 + kk * 32 + quad * 8];
#pragma unroll
        for (int s = 0; s < 2; s++) {
            int n = wv * 32 + s * 16 + l15;
            f32x4 acc = {};
#pragma unroll
            for (int kk = 0; kk < 4; kk++) {
                s16x8 bfr = *(const s16x8*)(w1t + (size_t)n * CZ + kk * 32 + quad * 8);
                acc = __builtin_amdgcn_mfma_f32_16x16x32_bf16(af1[kk], bfr, acc, 0, 0, 0);
            }
            float bv = b1[n];
#pragma unroll
            for (int r = 0; r < 4; r++)
                s_h[(quad * 4 + r) * 136 + n] = f2b(fmaxf(acc[r] + bv, 0.f));
        }
    }
    __syncthreads();
    // phase 2: stream w = h@W2+b2 through registers, contract immediately.
    // lane (quad,l15) acc[r] = w[e=quad*4+r][n=nt*16+l15]
    s16x8 af[4];
#pragma unroll
    for (int kk = 0; kk < 4; kk++)
        af[kk] = *(const s16x8*)&s_h[l15 * 136 + kk * 32 + quad * 8];
    float os[4]  = {0.f, 0.f, 0.f, 0.f};
    float sv2[4] = {0.f, 0.f, 0.f, 0.f};
    float ov0[4] = {0.f, 0.f, 0.f, 0.f};
    float ov1[4] = {0.f, 0.f, 0.f, 0.f};
    float ov2[4] = {0.f, 0.f, 0.f, 0.f};
    const int ib = l15 >> 3;
    for (int nt = wv; nt < 104; nt += 4) {
        const int n = nt * 16 + l15;
        float bv = b2[n];
        f32x4 acc = {};
#pragma unroll
        for (int kk = 0; kk < 4; kk++) {
            s16x8 bfr = *(const s16x8*)(w2t + (size_t)n * CZ + kk * 32 + quad * 8);
            acc = __builtin_amdgcn_mfma_f32_16x16x32_bf16(af[kk], bfr, acc, 0, 0, 0);
        }
        float w0 = acc[0] + bv, w1 = acc[1] + bv, w2 = acc[2] + bv, w3 = acc[3] + bv;
        if (nt < 64) {                      // w1 seg: i = nt>>1, j = (nt&1)*16+l15
            float4 f = *(const float4*)&s_xsT[nt >> 1][quad * 4];
            os[0] += w0 * f.x; os[1] += w1 * f.y; os[2] += w2 * f.z; os[3] += w3 * f.w;
        } else if (nt < 80) {               // w2 seg: i = (nt-64)*2+ib, j = l15&7
            float4 f = *(const float4*)&s_xsT[(nt - 64) * 2 + ib][quad * 4];
            sv2[0] += w0 * f.x; sv2[1] += w1 * f.y; sv2[2] += w2 * f.z; sv2[3] += w3 * f.w;
        } else if (nt < 84) {               // w3 seg: i = (nt-80)*2+ib, j = l15&7
            int i0 = ((nt - 80) * 2 + ib) * 3;
            float4 f0 = *(const float4*)&s_xvT[i0 + 0][quad * 4];
            float4 f1 = *(const float4*)&s_xvT[i0 + 1][quad * 4];
            float4 f2 = *(const float4*)&s_xvT[i0 + 2][quad * 4];
            ov0[0] += w0 * f0.x; ov0[1] += w1 * f0.y; ov0[2] += w2 * f0.z; ov0[3] += w3 * f0.w;
            ov1[0] += w0 * f1.x; ov1[1] += w1 * f1.y; ov1[2] += w2 * f1.z; ov1[3] += w3 * f1.w;
            ov2[0] += w0 * f2.x; ov2[1] += w1 * f2.y; ov2[2] += w2 * f2.z; ov2[3] += w3 * f2.w;
        } else if (nt < 100) {              // w4 seg: i = (nt-84)>>1, j = (nt&1)*16+l15
            float4 f = *(const float4*)&s_y4T[(nt - 84) >> 1][quad * 4];
            os[0] += w0 * f.x; os[1] += w1 * f.y; os[2] += w2 * f.z; os[3] += w3 * f.w;
        } else {                            // w5 seg: i = (nt-100)*2+ib, j = l15&7
            int i0 = ((nt - 100) * 2 + ib) * 3;
            float4 f0 = *(const float4*)&s_crT[i0 + 0][quad * 4];
            float4 f1 = *(const float4*)&s_crT[i0 + 1][quad * 4];
            float4 f2 = *(const float4*)&s_crT[i0 + 2][quad * 4];
            ov0[0] += w0 * f0.x; ov0[1] += w1 * f0.y; ov0[2] += w2 * f0.z; ov0[3] += w3 * f0.w;
            ov1[0] += w0 * f1.x; ov1[1] += w1 * f1.y; ov1[2] += w2 * f1.z; ov1[3] += w3 * f1.w;
            ov2[0] += w0 * f2.x; ov2[1] += w1 * f2.y; ov2[2] += w2 * f2.z; ov2[3] += w3 * f2.w;
        }
    }
    // reduce partials into LDS (a2 = a3/2 folded as 0.5*shv*s2)
    {
        const int jo = (wv & 1) * 16 + l15;
        const int jv3 = (l15 & 7) * 3;
#pragma unroll
        for (int r = 0; r < 4; r++) {
            int e = quad * 4 + r;
            atomicAdd(&s_os[e][jo], os[r]);
            float sv = 0.5f * sv2[r];
            atomicAdd(&s_ov[e][jv3 + 0], ov0[r] + s_shv[e][0] * sv);
            atomicAdd(&s_ov[e][jv3 + 1], ov1[r] + s_shv[e][1] * sv);
            atomicAdd(&s_ov[e][jv3 + 2], ov2[r] + s_shv[e][2] * sv);
        }
    }
    __syncthreads();
    // plain coalesced per-edge stores (a1 = 0.125, a3 = 1/sqrt(24)); icnt
    // applied in the aggregate kernel.
    for (int i = t; i < 512; i += 256) {
        int e = i >> 5, d = i & 31;
        tp_s[(size_t)(be + e) * 32 + d] = s_os[e][d] * 0.125f;
    }
    for (int i = t; i < 384; i += 256) {
        int e = i / 24, d = i - e * 24;
        tp_v[(size_t)(be + e) * 24 + d] = s_ov[e][d] * 0.2041241452319315f;
    }
}

// ---------------------------------------------------------------------------
// CSR build: inclusive scan of per-node counts (single block of 1024), then
// permutation fill.  Replaces init_misc (icnt folded in here).
// ---------------------------------------------------------------------------
__global__ __launch_bounds__(1024)
void scan_csr(const int* __restrict__ cnt, int* __restrict__ row_start,
              int* __restrict__ fillpos, float* __restrict__ icnt)
{
    __shared__ int tmp[1024];
    int t = threadIdx.x;
    int v = cnt[t];
    tmp[t] = v;
    __syncthreads();
    for (int o = 1; o < 1024; o <<= 1) {
        int x = (t >= o) ? tmp[t - o] : 0;
        __syncthreads();
        tmp[t] += x;
        __syncthreads();
    }
    int excl = tmp[t] - v;
    row_start[t] = excl;
    fillpos[t] = excl;
    if (t == 1023) row_start[1024] = tmp[1023];
    icnt[t] = 1.0f / (float)(v > 1 ? v : 1);
}

__global__ void fill_perm(const int* __restrict__ ei, int* __restrict__ fillpos,
                          int* __restrict__ perm)
{
    int e = blockIdx.x * 256 + threadIdx.x;
    if (e < NE) {
        int s = ei[NE + e];
        int p = atomicAdd(&fillpos[s], 1);
        perm[p] = e;
    }
}

// ---------------------------------------------------------------------------
// Segment-sum via CSR gather: block per node, 64 threads (t<32: scalar dims,
// 32<=t<56: vector dims).  Plain stores, zero atomics.
// ---------------------------------------------------------------------------
__global__ __launch_bounds__(64)
void aggregate(const float* __restrict__ tp_s, const float* __restrict__ tp_v,
               const int* __restrict__ perm, const int* __restrict__ row_start,
               const float* __restrict__ icnt,
               float* __restrict__ ags, float* __restrict__ agv)
{
    __shared__ int s_e[64];
    const int n = blockIdx.x, t = threadIdx.x;
    const int s = row_start[n], epe = row_start[n + 1];
    float acc = 0.f;
    for (int k0 = s; k0 < epe; k0 += 64) {
        int kk = k0 + t;
        s_e[t] = (kk < epe) ? perm[kk] : 0;
        __syncthreads();
        int m = epe - k0; if (m > 64) m = 64;
        for (int j = 0; j < m; j++) {
            int e = s_e[j];
            acc += (t < 32) ? tp_s[(size_t)e * 32 + t]
                            : tp_v[(size_t)e * 24 + (t - 32)];   // t>=56 reads pad, unused
        }
        __syncthreads();
    }
    acc *= icnt[n];
    if (t < 32) ags[n * CS + t] = acc;
    else if (t < 56) agv[n * 24 + (t - 32)] = acc;
}

// ---------------------------------------------------------------------------
__device__ __forceinline__ void trseg(int i, int R, int C,
                                      const float* __restrict__ s, bf16* __restrict__ d)
{
    int l = i / (R * C);
    int rem = i - l * R * C;
    int r = rem / C;
    int c = rem - r * C;
    d[(size_t)l * R * C + (size_t)c * R + r] = f2b(s[i]);
}

__global__ void transpose_all(const float* __restrict__ p0, const float* __restrict__ p1,
                              const float* __restrict__ p2, const float* __restrict__ p3,
                              const float* __restrict__ p4, const float* __restrict__ p5,
                              const float* __restrict__ p6, const float* __restrict__ p7,
                              bf16* d0, bf16* d1, bf16* d2, bf16* d3,
                              bf16* d4, bf16* d5, bf16* d6, bf16* d7)
{
    int i = blockIdx.x * 256 + threadIdx.x;
    const int S0 = INZ * CZ;            // ee_w1  212992
    const int S1 = CZ * CZ;             // ee_w2
    const int S2 = CZ * CZ;             // ee_w3
    const int S3 = NL * CZ * CZ;        // fc_w1
    const int S4 = NL * CZ * WN;        // fc_w2  851968
    const int S5 = NL * 384 * CZ;       // eu_w1
    const int S6 = NL * CZ * CZ;        // eu_w2
    const int S7 = NL * CZ * CZ;        // eu_w3
    if (i < S0) { trseg(i, INZ, CZ, p0, d0); return; } i -= S0;
    if (i < S1) { trseg(i, CZ, CZ, p1, d1); return; }  i -= S1;
    if (i < S2) { trseg(i, CZ, CZ, p2, d2); return; }  i -= S2;
    if (i < S3) { trseg(i, CZ, CZ, p3, d3); return; }  i -= S3;
    if (i < S4) { trseg(i, CZ, WN, p4, d4); return; }  i -= S4;
    if (i < S5) { trseg(i, 384, CZ, p5, d5); return; } i -= S5;
    if (i < S6) { trseg(i, CZ, CZ, p6, d6); return; }  i -= S6;
    if (i < S7) { trseg(i, CZ, CZ, p7, d7); return; }
}

__global__ __launch_bounds__(64)
void node_embed(const float* __restrict__ node_raw, const float* __restrict__ ne_ws,
                const float* __restrict__ ne_wv, float* __restrict__ xs, float* __restrict__ xv)
{
    int n = blockIdx.x, t = threadIdx.x;
    const float* nr = node_raw + (size_t)n * NRDIM;
    if (t < 32) {
        float acc = 0.f;
        for (int i = 0; i < INS; i++) acc += nr[i] * ne_ws[i * CS + t];
        xs[n * CS + t] = acc;
    } else if (t < 56) {
        int t2 = t - 32, j = t2 / 3, x = t2 - 3 * (t2 / 3);
        float acc = 0.f;
        for (int i = 0; i < INV; i++) acc += nr[INS + i * 3 + x] * ne_wv[i * CV + j];
        xv[n * 24 + t2] = acc;
    }
}

__global__ void count_src(const int* __restrict__ ei, int* __restrict__ cnt)
{
    int e = blockIdx.x * 256 + threadIdx.x;
    if (e < NE) atomicAdd(&cnt[ei[NE + e]], 1);
}

// add agg + batchnorm stats + apply.  40 blocks.  (agg buffers are fully
// overwritten by aggregate each layer -> no re-zeroing needed.)
__global__ __launch_bounds__(256)
void bnfused(float* __restrict__ xs, float* __restrict__ xv,
             const float* __restrict__ ags, const float* __restrict__ agv,
             const float* __restrict__ g, const float* __restrict__ b,
             const float* __restrict__ vg)
{
    __shared__ float red[8];
    __shared__ float stat[2];
    int c = blockIdx.x, t = threadIdx.x;
    if (c < 32) {
        float s = 0.f, s2 = 0.f;
        for (int n = t; n < NN; n += 256) {
            float v = xs[n * CS + c] + ags[n * CS + c];
            s += v; s2 += v * v;
        }
        for (int o = 32; o > 0; o >>= 1) { s += __shfl_down(s, o); s2 += __shfl_down(s2, o); }
        int w = t >> 6;
        if ((t & 63) == 0) { red[w * 2] = s; red[w * 2 + 1] = s2; }
        __syncthreads();
        if (t == 0) {
            float S = red[0] + red[2] + red[4] + red[6];
            float S2 = red[1] + red[3] + red[5] + red[7];
            float mean = S * (1.f / NN);
            float var = S2 * (1.f / NN) - mean * mean;
            stat[0] = mean;
            stat[1] = rsqrtf(var + 1e-5f);
        }
        __syncthreads();
        float mean = stat[0], rstd = stat[1], gg = g[c], bb = b[c];
        for (int n = t; n < NN; n += 256) {
            int ix = n * CS + c;
            float v = xs[ix] + ags[ix];
            xs[ix] = (v - mean) * rstd * gg + bb;
        }
    } else {
        int c2 = c - 32;
        float s = 0.f;
        for (int n = t; n < NN; n += 256) {
            float v0 = xv[n * 24 + c2 * 3 + 0] + agv[n * 24 + c2 * 3 + 0];
            float v1 = xv[n * 24 + c2 * 3 + 1] + agv[n * 24 + c2 * 3 + 1];
            float v2 = xv[n * 24 + c2 * 3 + 2] + agv[n * 24 + c2 * 3 + 2];
            s += v0 * v0 + v1 * v1 + v2 * v2;
        }
        for (int o = 32; o > 0; o >>= 1) s += __shfl_down(s, o);
        int w = t >> 6;
        if ((t & 63) == 0) red[w] = s;
        __syncthreads();
        if (t == 0) {
            float fn = (red[0] + red[1] + red[2] + red[3]) * (1.f / (3.f * NN));
            stat[0] = vg[c2] * rsqrtf(fn + 1e-5f);
        }
        __syncthreads();
        float scale = stat[0];
        for (int n = t; n < NN; n += 256) {
            for (int x = 0; x < 3; x++) {
                int ix = n * 24 + c2 * 3 + x;
                xv[ix] = (xv[ix] + agv[ix]) * scale;
            }
        }
    }
}

// a[n,128] = xs[n,:] @ eu_lin[l]
__global__ __launch_bounds__(128)
void lin_a(const float* __restrict__ xs, const float* __restrict__ eu_lin_l,
           bf16* __restrict__ a_b)
{
    __shared__ float sxs[32];
    int n = blockIdx.x, t = threadIdx.x;
    if (t < 32) sxs[t] = xs[n * CS + t];
    __syncthreads();
    float acc = 0.f;
    for (int c = 0; c < 32; c++) acc += sxs[c] * eu_lin_l[c * CZ + t];
    a_b[(size_t)n * CZ + t] = f2b(acc);
}

__global__ __launch_bounds__(128)
void final_out(const float* __restrict__ xs, const float* __restrict__ xv,
               const float* __restrict__ rot,
               const float* __restrict__ mu_w, const float* __restrict__ mu_b,
               const float* __restrict__ lv_w, const float* __restrict__ lv_b,
               float* __restrict__ out)
{
    __shared__ float feat[56];
    int n = blockIdx.x, t = threadIdx.x;
    if (t < 32) feat[t] = xs[n * CS + t];
    else if (t < 56) {
        int t2 = t - 32, c = t2 / 3, y = t2 - 3 * (t2 / 3);
        float acc = 0.f;
        for (int x = 0; x < 3; x++)
            acc += rot[n * 9 + x * 3 + y] * xv[n * 24 + c * 3 + x];
        feat[t] = acc;
    }
    __syncthreads();
    float mu = mu_b[t], lv = lv_b[t];
    for (int d = 0; d < 56; d++) {
        float f = feat[d];
        mu += f * mu_w[d * 128 + t];
        lv += f * lv_w[d * 128 + t];
    }
    out[(size_t)n * 128 + t] = mu;
    out[(size_t)NN * 128 + (size_t)n * 128 + t] = lv;
}

// ---------------------------------------------------------------------------
extern "C" void kernel_launch(void* const* d_in, const int* in_sizes, int n_in,
                              void* d_out, int out_size, void* d_ws, size_t ws_size,
                              hipStream_t stream)
{
    (void)in_sizes; (void)n_in; (void)out_size; (void)ws_size;
    const float* node_raw  = (const float*)d_in[0];
    const float* edge_raw  = (const float*)d_in[1];
    const float* edge_vecs = (const float*)d_in[2];
    const float* rot       = (const float*)d_in[3];
    const int*   ei        = (const int*  )d_in[4];
    const float* ee_w1 = (const float*)d_in[5];
    const float* ee_b1 = (const float*)d_in[6];
    const float* ee_w2 = (const float*)d_in[7];
    const float* ee_b2 = (const float*)d_in[8];
    const float* ee_w3 = (const float*)d_in[9];
    const float* ee_b3 = (const float*)d_in[10];
    const float* ee_ln_g = (const float*)d_in[11];
    const float* ee_ln_b = (const float*)d_in[12];
    const float* ne_ws = (const float*)d_in[13];
    const float* ne_wv = (const float*)d_in[14];
    const float* fc_w1 = (const float*)d_in[15];
    const float* fc_b1 = (const float*)d_in[16];
    const float* fc_w2 = (const float*)d_in[17];
    const float* fc_b2 = (const float*)d_in[18];
    const float* bn_g  = (const float*)d_in[19];
    const float* bn_b  = (const float*)d_in[20];
    const float* bn_vg = (const float*)d_in[21];
    const float* eu_lin = (const float*)d_in[22];
    const float* eu_w1 = (const float*)d_in[23];
    const float* eu_b1 = (const float*)d_in[24];
    const float* eu_w2 = (const float*)d_in[25];
    const float* eu_b2 = (const float*)d_in[26];
    const float* eu_w3 = (const float*)d_in[27];
    const float* eu_b3 = (const float*)d_in[28];
    const float* eu_ln_g = (const float*)d_in[29];
    const float* eu_ln_b = (const float*)d_in[30];
    const float* mu_w = (const float*)d_in[31];
    const float* mu_b = (const float*)d_in[32];
    const float* lv_w = (const float*)d_in[33];
    const float* lv_b = (const float*)d_in[34];

    char* ws = (char*)d_ws;
    size_t off = 0;
    auto alloc = [&](size_t bytes) -> void* {
        void* p = ws + off;
        off += (bytes + 255) & ~(size_t)255;
        return p;
    };
    bf16*  ef_b  = (bf16*) alloc((size_t)NE * CZ * 2);     // residual stream
    bf16*  buf_a = (bf16*) alloc((size_t)NE * CZ * 2);
    float* xs    = (float*)alloc((size_t)NN * CS * 4);
    float* xv    = (float*)alloc((size_t)NN * 24 * 4);
    float* ags   = (float*)alloc((size_t)NN * CS * 4);
    float* agv   = (float*)alloc((size_t)NN * 24 * 4);
    int*   cnti  = (int*)  alloc((size_t)NN * 4);
    float* icnt  = (float*)alloc((size_t)NN * 4);
    bf16*  a_b   = (bf16*) alloc((size_t)NN * CZ * 2);
    float* tp_s  = (float*)alloc((size_t)NE * 32 * 4);
    float* tp_v  = (float*)alloc((size_t)NE * 24 * 4 + 64);   // +pad for lane 56-63 reads
    int*   perm  = (int*)  alloc((size_t)NE * 4);
    int*   row_start = (int*)alloc((size_t)(NN + 1) * 4);
    int*   fillpos   = (int*)alloc((size_t)NN * 4);
    bf16* ee_w1t = (bf16*)alloc((size_t)INZ * CZ * 2);
    bf16* ee_w2t = (bf16*)alloc((size_t)CZ * CZ * 2);
    bf16* ee_w3t = (bf16*)alloc((size_t)CZ * CZ * 2);
    bf16* fc_w1t = (bf16*)alloc((size_t)NL * CZ * CZ * 2);
    bf16* fc_w2t = (bf16*)alloc((size_t)NL * WN * CZ * 2);
    bf16* eu_w1t = (bf16*)alloc((size_t)NL * 384 * CZ * 2);
    bf16* eu_w2t = (bf16*)alloc((size_t)NL * CZ * CZ * 2);
    bf16* eu_w3t = (bf16*)alloc((size_t)NL * CZ * CZ * 2);

    const int TRN = INZ*CZ + 2*CZ*CZ + NL*CZ*CZ + NL*CZ*WN + NL*384*CZ + 2*NL*CZ*CZ;
    transpose_all<<<(TRN + 255) / 256, 256, 0, stream>>>(
        ee_w1, ee_w2, ee_w3, fc_w1, fc_w2, eu_w1, eu_w2, eu_w3,
        ee_w1t, ee_w2t, ee_w3t, fc_w1t, fc_w2t, eu_w1t, eu_w2t, eu_w3t);

    node_embed<<<NN, 64, 0, stream>>>(node_raw, ne_ws, ne_wv, xs, xv);
    hipMemsetAsync(cnti, 0, NN * 4, stream);
    count_src<<<NE / 256, 256, 0, stream>>>(ei, cnti);
    scan_csr<<<1, 1024, 0, stream>>>(cnti, row_start, fillpos, icnt);
    fill_perm<<<NE / 256, 256, 0, stream>>>(ei, fillpos, perm);

    const int GE = NE / 64;   // 480
    // edge embedding: ee1 (K=1664 fp32 A) then fused ee2+ee3+LN
    gemm64<1, 1, 0><<<GE, 256, 0, stream>>>(edge_raw, ee_w1t, ee_b1, buf_a, NE, INZ, nullptr, nullptr, nullptr);
    mlp2<0><<<GE, 256, 0, stream>>>(buf_a, ee_w2t, ee_b2, ee_w3t, ee_b3, ee_ln_g, ee_ln_b, ef_b);

    for (int l = 0; l < NL; l++) {
        fc2_tp<<<NE / 16, 256, 0, stream>>>(
            ef_b, fc_w1t + (size_t)l * CZ * CZ, fc_b1 + l * CZ,
            fc_w2t + (size_t)l * WN * CZ, fc_b2 + l * WN,
            ei, edge_vecs, xs, xv, tp_s, tp_v);
        aggregate<<<NN, 64, 0, stream>>>(tp_s, tp_v, perm, row_start, icnt, ags, agv);
        bnfused<<<40, 256, 0, stream>>>(xs, xv, ags, agv,
                                        bn_g + l * CS, bn_b + l * CS, bn_vg + l * CV);
        lin_a<<<NN, 128, 0, stream>>>(xs, eu_lin + (size_t)l * CS * CZ, a_b);
        gemm64<1, 0, 1><<<GE, 256, 0, stream>>>(
            nullptr, eu_w1t + (size_t)l * 384 * CZ, eu_b1 + l * CZ, buf_a, NE, 384, a_b, ef_b, ei);
        mlp2<1><<<GE, 256, 0, stream>>>(buf_a, eu_w2t + (size_t)l * CZ * CZ, eu_b2 + l * CZ,
                                        eu_w3t + (size_t)l * CZ * CZ, eu_b3 + l * CZ,
                                        eu_ln_g + l * CZ, eu_ln_b + l * CZ, ef_b);
    }

    final_out<<<NN, 128, 0, stream>>>(xs, xv, rot, mu_w, mu_b, lv_w, lv_b, (float*)d_out);
}

// Round 3
// 946.640 us; speedup vs baseline: 1.2746x; 1.2746x over previous
//
#include <hip/hip_runtime.h>
#include <hip/hip_bf16.h>

typedef __hip_bfloat16 bf16;
typedef __attribute__((ext_vector_type(8))) short s16x8;   // 8 bf16 (4 VGPRs) MFMA frag
typedef __attribute__((ext_vector_type(4))) float f32x4;   // MFMA accumulator

#define NN 1024      // nodes
#define NE 30720     // edges
#define CS 32
#define CV 8
#define CZ 128
#define INS 28
#define INV 37
#define NRDIM 139    // 28 + 3*37
#define INZ 1664
#define WN 1664      // WEIGHT_NUMEL
#define NL 4

__device__ __forceinline__ float b2f(bf16 x) { return __bfloat162float(x); }
__device__ __forceinline__ bf16 f2b(float x) { return __float2bfloat16(x); }

// ---------------------------------------------------------------------------
// All weight matrices are stored FRAGMENT-LINEAR: for a [R rows k][C cols n]
// matrix, element (k,n) lives at ((n>>4)*(R/32) + (k>>5))*512 + ((k>>3)&3)*128
// + (n&15)*8 + (k&7).  A wave's MFMA B-fragment load for (nt=n>>4, kk=k>>5)
// is then ONE contiguous 1 KB load at base + lane*16 — no 256B-strided lane
// divergence (the old pattern fragmented every load into 16 L2 requests and
// made fc2_tp L2-request-bound at 5.3 TB/s effective).
// ---------------------------------------------------------------------------

// Skinny MFMA GEMM, N=128 fixed (used for ee1 K=1664 fp32-A and eu1 gather).
// Tile M=64 -> grid 480. AF32: A fp32 converted in staging. GATHER: row e =
// [a_b[dst[e]] | a_b[src[e]] | ef_b[e]] (K=384).  B read fragment-linear
// directly from global (no B LDS staging).
template<int RELU, int AF32, int GATHER>
__global__ __launch_bounds__(256)
void gemm64(const void* __restrict__ Ap, const bf16* __restrict__ Bf,
            const float* __restrict__ bias, bf16* __restrict__ Cp,
            int M, int K,
            const bf16* __restrict__ g_a, const bf16* __restrict__ g_ef,
            const int* __restrict__ g_ei)
{
    __shared__ __align__(16) bf16 la[64 * 40];
    const int bm = blockIdx.x * 64;
    const int tid = threadIdx.x;
    const int lane = tid & 63;
    const int wv = tid >> 6;
    const int lr = tid >> 1;
    const int lc = (tid & 1) * 16;
    const int l15 = lane & 15;
    const int quad = lane >> 4;
    const int K32 = K >> 5;
    f32x4 acc[4][2] = {};
    const bf16*  ga16 = (const bf16*) Ap + (size_t)(bm + lr) * K + lc;
    const float* ga32 = (const float*)Ap + (size_t)(bm + lr) * K + lc;
    int gdst = 0, gsrc = 0, grow = 0;
    if (GATHER && tid < 128) {
        grow = bm + lr;
        gdst = g_ei[grow];
        gsrc = g_ei[NE + grow];
    }
    for (int k0 = 0; k0 < K; k0 += 32) {
        union { bf16 h[16]; float4 q[2]; } pa;
        if (tid < 128) {
            if (AF32) {
                float4 f0 = *(const float4*)(ga32 + k0);
                float4 f1 = *(const float4*)(ga32 + k0 + 4);
                float4 f2 = *(const float4*)(ga32 + k0 + 8);
                float4 f3 = *(const float4*)(ga32 + k0 + 12);
                pa.h[0]=f2b(f0.x); pa.h[1]=f2b(f0.y); pa.h[2]=f2b(f0.z); pa.h[3]=f2b(f0.w);
                pa.h[4]=f2b(f1.x); pa.h[5]=f2b(f1.y); pa.h[6]=f2b(f1.z); pa.h[7]=f2b(f1.w);
                pa.h[8]=f2b(f2.x); pa.h[9]=f2b(f2.y); pa.h[10]=f2b(f2.z); pa.h[11]=f2b(f2.w);
                pa.h[12]=f2b(f3.x); pa.h[13]=f2b(f3.y); pa.h[14]=f2b(f3.z); pa.h[15]=f2b(f3.w);
            } else if (GATHER) {
                int kk = k0 + lc;
                const bf16* src;
                if (kk < 128)      src = g_a  + (size_t)gdst * CZ + kk;
                else if (kk < 256) src = g_a  + (size_t)gsrc * CZ + (kk - 128);
                else               src = g_ef + (size_t)grow * CZ + (kk - 256);
                pa.q[0] = *(const float4*)src;
                pa.q[1] = *(const float4*)(src + 8);
            } else {
                pa.q[0] = *(const float4*)(ga16 + k0);
                pa.q[1] = *(const float4*)(ga16 + k0 + 8);
            }
        }
        // B fragments: coalesced 1 KB loads, independent of LDS
        s16x8 bfr[2];
#pragma unroll
        for (int ni = 0; ni < 2; ni++)
            bfr[ni] = *(const s16x8*)(Bf + (size_t)(((wv * 2 + ni) * K32 + (k0 >> 5)) * 512) + lane * 8);
        __syncthreads();
        if (tid < 128) {
            *(float4*)&la[lr * 40 + lc]     = pa.q[0];
            *(float4*)&la[lr * 40 + lc + 8] = pa.q[1];
        }
        __syncthreads();
        s16x8 af[4];
#pragma unroll
        for (int mi = 0; mi < 4; mi++)
            af[mi] = *(const s16x8*)&la[(mi * 16 + l15) * 40 + quad * 8];
#pragma unroll
        for (int mi = 0; mi < 4; mi++)
#pragma unroll
            for (int ni = 0; ni < 2; ni++)
                acc[mi][ni] = __builtin_amdgcn_mfma_f32_16x16x32_bf16(af[mi], bfr[ni], acc[mi][ni], 0, 0, 0);
    }
#pragma unroll
    for (int ni = 0; ni < 2; ni++) {
        const int col = wv * 32 + ni * 16 + l15;
        const float bv = bias[col];
#pragma unroll
        for (int mi = 0; mi < 4; mi++) {
            const int row0 = bm + mi * 16 + quad * 4;
#pragma unroll
            for (int r = 0; r < 4; r++) {
                float v = acc[mi][ni][r] + bv;
                if (RELU) v = fmaxf(v, 0.f);
                Cp[(size_t)(row0 + r) * CZ + col] = f2b(v);
            }
        }
    }
}

// ---------------------------------------------------------------------------
// Fused MLP tail: u2 = relu(A@W2+b2); u3 = u2@W3+b3 (+resid); LN -> efb (bf16)
// Block = 64 rows.  W2/W3 fragment-linear (coalesced loads).
// ---------------------------------------------------------------------------
template<int RESID>
__global__ __launch_bounds__(256)
void mlp2(const bf16* __restrict__ A,
          const bf16* __restrict__ w2f, const float* __restrict__ b2,
          const bf16* __restrict__ w3f, const float* __restrict__ b3,
          const float* __restrict__ g, const float* __restrict__ bb,
          bf16* efb)
{
    __shared__ __align__(16) bf16 s_a[64 * 136];
    __shared__ __align__(16) bf16 s_u[64 * 136];
    __shared__ float s_o[64 * 132];
    const int bm = blockIdx.x * 64;
    const int t = threadIdx.x;
    const int lane = t & 63;
    const int wv = t >> 6;
    const int l15 = lane & 15;
    const int quad = lane >> 4;
    {   // stage A tile 64x128
        int r = t >> 2, c0 = (t & 3) * 32;
        const float4* s4 = (const float4*)(A + (size_t)(bm + r) * CZ + c0);
        float4* d4 = (float4*)&s_a[r * 136 + c0];
        d4[0] = s4[0]; d4[1] = s4[1]; d4[2] = s4[2]; d4[3] = s4[3];
    }
    __syncthreads();
    s16x8 af[4][4];
#pragma unroll
    for (int mi = 0; mi < 4; mi++)
#pragma unroll
        for (int kk = 0; kk < 4; kk++)
            af[mi][kk] = *(const s16x8*)&s_a[(mi * 16 + l15) * 136 + kk * 32 + quad * 8];
    // stage 1: relu(A@W2+b2) -> s_u
#pragma unroll
    for (int s = 0; s < 2; s++) {
        int n = wv * 32 + s * 16 + l15;
        f32x4 acc[4] = {};
#pragma unroll
        for (int kk = 0; kk < 4; kk++) {
            s16x8 bfr = *(const s16x8*)(w2f + (size_t)(((wv * 2 + s) * 4 + kk) * 512) + lane * 8);
#pragma unroll
            for (int mi = 0; mi < 4; mi++)
                acc[mi] = __builtin_amdgcn_mfma_f32_16x16x32_bf16(af[mi][kk], bfr, acc[mi], 0, 0, 0);
        }
        float bv = b2[n];
#pragma unroll
        for (int mi = 0; mi < 4; mi++)
#pragma unroll
            for (int r = 0; r < 4; r++)
                s_u[(mi * 16 + quad * 4 + r) * 136 + n] = f2b(fmaxf(acc[mi][r] + bv, 0.f));
    }
    __syncthreads();
#pragma unroll
    for (int mi = 0; mi < 4; mi++)
#pragma unroll
        for (int kk = 0; kk < 4; kk++)
            af[mi][kk] = *(const s16x8*)&s_u[(mi * 16 + l15) * 136 + kk * 32 + quad * 8];
    // stage 2: u2@W3+b3 -> s_o (f32)
#pragma unroll
    for (int s = 0; s < 2; s++) {
        int n = wv * 32 + s * 16 + l15;
        f32x4 acc[4] = {};
#pragma unroll
        for (int kk = 0; kk < 4; kk++) {
            s16x8 bfr = *(const s16x8*)(w3f + (size_t)(((wv * 2 + s) * 4 + kk) * 512) + lane * 8);
#pragma unroll
            for (int mi = 0; mi < 4; mi++)
                acc[mi] = __builtin_amdgcn_mfma_f32_16x16x32_bf16(af[mi][kk], bfr, acc[mi], 0, 0, 0);
        }
        float bv = b3[n];
#pragma unroll
        for (int mi = 0; mi < 4; mi++)
#pragma unroll
            for (int r = 0; r < 4; r++)
                s_o[(mi * 16 + quad * 4 + r) * 132 + n] = acc[mi][r] + bv;
    }
    __syncthreads();
    // LN per row: 4 lanes per row, 32 cols each
    {
        int row = wv * 16 + (lane >> 2);
        int q = lane & 3;
        int col0 = q * 32;
        size_t gbase = (size_t)(bm + row) * CZ;
        float s = 0.f, s2 = 0.f;
        for (int i = 0; i < 32; i++) {
            float x = s_o[row * 132 + col0 + i];
            if (RESID) x += b2f(efb[gbase + col0 + i]);
            s += x; s2 += x * x;
        }
        s  += __shfl_xor(s, 1);  s2 += __shfl_xor(s2, 1);
        s  += __shfl_xor(s, 2);  s2 += __shfl_xor(s2, 2);
        float mean = s * (1.f / 128.f);
        float var  = s2 * (1.f / 128.f) - mean * mean;
        float rstd = rsqrtf(var + 1e-5f);
        for (int i = 0; i < 32; i++) {
            int col = col0 + i;
            float x = s_o[row * 132 + col];
            if (RESID) x += b2f(efb[gbase + col]);
            efb[gbase + col] = f2b((x - mean) * rstd * g[col] + bb[col]);
        }
    }
}

// ---------------------------------------------------------------------------
// Fused fc1 + fc2 + tensor product.  Block = 64 edges (grid 480).
// Key change vs the 140-156us plateau: each block now amortizes the full
// 426 KB W2 stream over 64 edges (4x fewer L2 bytes+requests dispatch-wide:
// 818 MB -> 204 MB) and every W2 load is ONE coalesced 1 KB wave load
// (fragment-linear layout) instead of 16 scattered 64 B line requests.
// Phase 2 consumes w = h@W2+b2 in registers (af[4][4] A-frags, 4 MFMAs per
// B-fragment), accumulating 20 TP partials per lane per m-tile.
// ---------------------------------------------------------------------------
__global__ __launch_bounds__(256, 2)
void fc2_tp(const bf16* __restrict__ ef,
            const bf16* __restrict__ w1f, const float* __restrict__ b1,
            const bf16* __restrict__ w2f, const float* __restrict__ b2,
            const int* __restrict__ ei, const float* __restrict__ edge_vecs,
            const float* __restrict__ xs, const float* __restrict__ xv,
            float* __restrict__ tp_s, float* __restrict__ tp_v)
{
    __shared__ __align__(16) bf16 s_a[64 * 136];    // 17408
    __shared__ __align__(16) bf16 s_h[64 * 136];    // 17408
    __shared__ __align__(16) float s_xsT[32][64];   //  8192  xs[dst[e]][i] -> [i][e]
    __shared__ __align__(16) float s_xvT[24][64];   //  6144
    __shared__ __align__(16) float s_crT[24][64];   //  6144  cross, pre-scaled 1/sqrt(2)
    __shared__ __align__(16) float s_y4T[8][64];    //  2048  dot, pre-scaled 2/sqrt(3)
    __shared__ __align__(16) float s_b2[WN];        //  6656
    __shared__ float s_shv[64][3];                  //   768
    __shared__ int s_dst[64];                       //   256
    __shared__ float s_os[64][32];                  //  8192
    __shared__ float s_ov[64][24];                  //  6144   total ~79.4 KB -> 2 blk/CU
    const int be = blockIdx.x * 64;
    const int t = threadIdx.x;
    const int lane = t & 63;
    const int wv = t >> 6;
    const int l15 = lane & 15;
    const int quad = lane >> 4;
    const int q4 = quad * 4;

    if (t < 64) {
        int e = be + t;
        s_dst[t] = ei[e];
        float vx = edge_vecs[e * 3 + 0];
        float vy = edge_vecs[e * 3 + 1];
        float vz = edge_vecs[e * 3 + 2];
        float sc = 1.7320508075688772f / (sqrtf(vx * vx + vy * vy + vz * vz) + 1e-8f);
        s_shv[t][0] = vx * sc; s_shv[t][1] = vy * sc; s_shv[t][2] = vz * sc;
    }
    for (int i = t; i < 64 * 32; i += 256) ((float*)s_os)[i] = 0.f;
    for (int i = t; i < 64 * 24; i += 256) ((float*)s_ov)[i] = 0.f;
    for (int i = t; i < WN; i += 256) s_b2[i] = b2[i];
    {   // stage ef tile 64x128
        int r = t >> 2, c0 = (t & 3) * 32;
        const float4* s4 = (const float4*)(ef + (size_t)(be + r) * CZ + c0);
        float4* d4 = (float4*)&s_a[r * 136 + c0];
        d4[0] = s4[0]; d4[1] = s4[1]; d4[2] = s4[2]; d4[3] = s4[3];
    }
    __syncthreads();
    for (int i = t; i < 64 * 32; i += 256) { int e = i & 63, c = i >> 6; s_xsT[c][e] = xs[s_dst[e] * CS + c]; }
    for (int i = t; i < 64 * 24; i += 256) { int e = i & 63, c = i >> 6; s_xvT[c][e] = xv[s_dst[e] * 24 + c]; }
    __syncthreads();
    for (int i2 = t; i2 < 512; i2 += 256) {   // y4 + cross, path-constants folded
        int e = i2 & 63, i = i2 >> 6;
        float h0 = s_shv[e][0], h1 = s_shv[e][1], h2 = s_shv[e][2];
        float x0 = s_xvT[i * 3 + 0][e], x1 = s_xvT[i * 3 + 1][e], x2 = s_xvT[i * 3 + 2][e];
        s_y4T[i][e] = 1.1547005383792515f * (x0 * h0 + x1 * h1 + x2 * h2);
        s_crT[i * 3 + 0][e] = 0.7071067811865476f * (x1 * h2 - x2 * h1);
        s_crT[i * 3 + 1][e] = 0.7071067811865476f * (x2 * h0 - x0 * h2);
        s_crT[i * 3 + 2][e] = 0.7071067811865476f * (x0 * h1 - x1 * h0);
    }
    // phase 1: h = relu(ef@W1+b1), M=64 N=128 K=128
    {
        s16x8 af1[4][4];
#pragma unroll
        for (int mi = 0; mi < 4; mi++)
#pragma unroll
            for (int kk = 0; kk < 4; kk++)
                af1[mi][kk] = *(const s16x8*)&s_a[(mi * 16 + l15) * 136 + kk * 32 + quad * 8];
#pragma unroll
        for (int s = 0; s < 2; s++) {
            int n = wv * 32 + s * 16 + l15;
            f32x4 acc[4] = {};
#pragma unroll
            for (int kk = 0; kk < 4; kk++) {
                s16x8 bfr = *(const s16x8*)(w1f + (size_t)(((wv * 2 + s) * 4 + kk) * 512) + lane * 8);
#pragma unroll
                for (int mi = 0; mi < 4; mi++)
                    acc[mi] = __builtin_amdgcn_mfma_f32_16x16x32_bf16(af1[mi][kk], bfr, acc[mi], 0, 0, 0);
            }
            float bv = b1[n];
#pragma unroll
            for (int mi = 0; mi < 4; mi++)
#pragma unroll
                for (int r = 0; r < 4; r++)
                    s_h[(mi * 16 + quad * 4 + r) * 136 + n] = f2b(fmaxf(acc[mi][r] + bv, 0.f));
        }
    }
    __syncthreads();
    // phase 2: stream w = h@W2+b2 through registers, contract immediately.
    // lane (quad,l15), m-tile mi: ac[mi][r] = w[e=mi*16+quad*4+r][n=nt*16+l15]
    s16x8 af[4][4];
#pragma unroll
    for (int mi = 0; mi < 4; mi++)
#pragma unroll
        for (int kk = 0; kk < 4; kk++)
            af[mi][kk] = *(const s16x8*)&s_h[(mi * 16 + l15) * 136 + kk * 32 + quad * 8];
    float os[4][4] = {}, sv2[4][4] = {}, ov0[4][4] = {}, ov1[4][4] = {}, ov2[4][4] = {};
    const int ib = l15 >> 3;
    for (int nt = wv; nt < 104; nt += 4) {
        const float bv = s_b2[nt * 16 + l15];
        const bf16* wb = w2f + (size_t)(nt * 4) * 512 + lane * 8;
        s16x8 bfr[4];
#pragma unroll
        for (int kk = 0; kk < 4; kk++)
            bfr[kk] = *(const s16x8*)(wb + kk * 512);
        f32x4 ac[4] = {};
#pragma unroll
        for (int kk = 0; kk < 4; kk++)
#pragma unroll
            for (int mi = 0; mi < 4; mi++)
                ac[mi] = __builtin_amdgcn_mfma_f32_16x16x32_bf16(af[mi][kk], bfr[kk], ac[mi], 0, 0, 0);
        if (nt < 64) {                      // w1 seg: i = nt>>1, j = (nt&1)*16+l15
            const int i = nt >> 1;
#pragma unroll
            for (int mi = 0; mi < 4; mi++) {
                float4 f = *(const float4*)&s_xsT[i][mi * 16 + q4];
                os[mi][0] += (ac[mi][0] + bv) * f.x; os[mi][1] += (ac[mi][1] + bv) * f.y;
                os[mi][2] += (ac[mi][2] + bv) * f.z; os[mi][3] += (ac[mi][3] + bv) * f.w;
            }
        } else if (nt < 80) {               // w2 seg: i = (nt-64)*2+ib, j = l15&7
            const int i = (nt - 64) * 2 + ib;
#pragma unroll
            for (int mi = 0; mi < 4; mi++) {
                float4 f = *(const float4*)&s_xsT[i][mi * 16 + q4];
                sv2[mi][0] += (ac[mi][0] + bv) * f.x; sv2[mi][1] += (ac[mi][1] + bv) * f.y;
                sv2[mi][2] += (ac[mi][2] + bv) * f.z; sv2[mi][3] += (ac[mi][3] + bv) * f.w;
            }
        } else if (nt < 84) {               // w3 seg: i = (nt-80)*2+ib, j = l15&7
            const int i0 = ((nt - 80) * 2 + ib) * 3;
#pragma unroll
            for (int mi = 0; mi < 4; mi++) {
                float4 f0 = *(const float4*)&s_xvT[i0 + 0][mi * 16 + q4];
                float4 f1 = *(const float4*)&s_xvT[i0 + 1][mi * 16 + q4];
                float4 f2 = *(const float4*)&s_xvT[i0 + 2][mi * 16 + q4];
                float w0 = ac[mi][0] + bv, w1 = ac[mi][1] + bv, w2 = ac[mi][2] + bv, w3 = ac[mi][3] + bv;
                ov0[mi][0] += w0 * f0.x; ov0[mi][1] += w1 * f0.y; ov0[mi][2] += w2 * f0.z; ov0[mi][3] += w3 * f0.w;
                ov1[mi][0] += w0 * f1.x; ov1[mi][1] += w1 * f1.y; ov1[mi][2] += w2 * f1.z; ov1[mi][3] += w3 * f1.w;
                ov2[mi][0] += w0 * f2.x; ov2[mi][1] += w1 * f2.y; ov2[mi][2] += w2 * f2.z; ov2[mi][3] += w3 * f2.w;
            }
        } else if (nt < 100) {              // w4 seg: i = (nt-84)>>1, j = (nt&1)*16+l15
            const int i = (nt - 84) >> 1;
#pragma unroll
            for (int mi = 0; mi < 4; mi++) {
                float4 f = *(const float4*)&s_y4T[i][mi * 16 + q4];
                os[mi][0] += (ac[mi][0] + bv) * f.x; os[mi][1] += (ac[mi][1] + bv) * f.y;
                os[mi][2] += (ac[mi][2] + bv) * f.z; os[mi][3] += (ac[mi][3] + bv) * f.w;
            }
        } else {                            // w5 seg: i = (nt-100)*2+ib, j = l15&7
            const int i0 = ((nt - 100) * 2 + ib) * 3;
#pragma unroll
            for (int mi = 0; mi < 4; mi++) {
                float4 f0 = *(const float4*)&s_crT[i0 + 0][mi * 16 + q4];
                float4 f1 = *(const float4*)&s_crT[i0 + 1][mi * 16 + q4];
                float4 f2 = *(const float4*)&s_crT[i0 + 2][mi * 16 + q4];
                float w0 = ac[mi][0] + bv, w1 = ac[mi][1] + bv, w2 = ac[mi][2] + bv, w3 = ac[mi][3] + bv;
                ov0[mi][0] += w0 * f0.x; ov0[mi][1] += w1 * f0.y; ov0[mi][2] += w2 * f0.z; ov0[mi][3] += w3 * f0.w;
                ov1[mi][0] += w0 * f1.x; ov1[mi][1] += w1 * f1.y; ov1[mi][2] += w2 * f1.z; ov1[mi][3] += w3 * f1.w;
                ov2[mi][0] += w0 * f2.x; ov2[mi][1] += w1 * f2.y; ov2[mi][2] += w2 * f2.z; ov2[mi][3] += w3 * f2.w;
            }
        }
    }
    // reduce partials into LDS (a2 = a3/2 folded as 0.5*shv*s2)
    {
        const int jo = (wv & 1) * 16 + l15;
        const int jv3 = (l15 & 7) * 3;
#pragma unroll
        for (int mi = 0; mi < 4; mi++)
#pragma unroll
            for (int r = 0; r < 4; r++) {
                int e = mi * 16 + quad * 4 + r;
                atomicAdd(&s_os[e][jo], os[mi][r]);
                float sv = 0.5f * sv2[mi][r];
                atomicAdd(&s_ov[e][jv3 + 0], ov0[mi][r] + s_shv[e][0] * sv);
                atomicAdd(&s_ov[e][jv3 + 1], ov1[mi][r] + s_shv[e][1] * sv);
                atomicAdd(&s_ov[e][jv3 + 2], ov2[mi][r] + s_shv[e][2] * sv);
            }
    }
    __syncthreads();
    // plain coalesced per-edge stores (a1 = 0.125, a3 = 1/sqrt(24))
    for (int i = t; i < 64 * 32; i += 256) {
        int e = i >> 5, d = i & 31;
        tp_s[(size_t)(be + e) * 32 + d] = s_os[e][d] * 0.125f;
    }
    for (int i = t; i < 64 * 24; i += 256) {
        int e = i / 24, d = i - e * 24;
        tp_v[(size_t)(be + e) * 24 + d] = s_ov[e][d] * 0.2041241452319315f;
    }
}

// ---------------------------------------------------------------------------
// CSR build: inclusive scan of per-node counts (single block of 1024), then
// permutation fill.
// ---------------------------------------------------------------------------
__global__ __launch_bounds__(1024)
void scan_csr(const int* __restrict__ cnt, int* __restrict__ row_start,
              int* __restrict__ fillpos, float* __restrict__ icnt)
{
    __shared__ int tmp[1024];
    int t = threadIdx.x;
    int v = cnt[t];
    tmp[t] = v;
    __syncthreads();
    for (int o = 1; o < 1024; o <<= 1) {
        int x = (t >= o) ? tmp[t - o] : 0;
        __syncthreads();
        tmp[t] += x;
        __syncthreads();
    }
    int excl = tmp[t] - v;
    row_start[t] = excl;
    fillpos[t] = excl;
    if (t == 1023) row_start[1024] = tmp[1023];
    icnt[t] = 1.0f / (float)(v > 1 ? v : 1);
}

__global__ void fill_perm(const int* __restrict__ ei, int* __restrict__ fillpos,
                          int* __restrict__ perm)
{
    int e = blockIdx.x * 256 + threadIdx.x;
    if (e < NE) {
        int s = ei[NE + e];
        int p = atomicAdd(&fillpos[s], 1);
        perm[p] = e;
    }
}

// ---------------------------------------------------------------------------
// Segment-sum via CSR gather: block per node, 64 threads.
// ---------------------------------------------------------------------------
__global__ __launch_bounds__(64)
void aggregate(const float* __restrict__ tp_s, const float* __restrict__ tp_v,
               const int* __restrict__ perm, const int* __restrict__ row_start,
               const float* __restrict__ icnt,
               float* __restrict__ ags, float* __restrict__ agv)
{
    __shared__ int s_e[64];
    const int n = blockIdx.x, t = threadIdx.x;
    const int s = row_start[n], epe = row_start[n + 1];
    float acc = 0.f;
    for (int k0 = s; k0 < epe; k0 += 64) {
        int kk = k0 + t;
        s_e[t] = (kk < epe) ? perm[kk] : 0;
        __syncthreads();
        int m = epe - k0; if (m > 64) m = 64;
        for (int j = 0; j < m; j++) {
            int e = s_e[j];
            acc += (t < 32) ? tp_s[(size_t)e * 32 + t]
                            : tp_v[(size_t)e * 24 + (t - 32)];   // t>=56 reads pad, unused
        }
        __syncthreads();
    }
    acc *= icnt[n];
    if (t < 32) ags[n * CS + t] = acc;
    else if (t < 56) agv[n * 24 + (t - 32)] = acc;
}

// ---------------------------------------------------------------------------
// Weight repack: fragment-linear for a [R][C] matrix (leading layer dim l).
// dest(k,n) = ((n>>4)*(R/32) + (k>>5))*512 + ((k>>3)&3)*128 + (n&15)*8 + (k&7)
// ---------------------------------------------------------------------------
__device__ __forceinline__ void fragseg(int i, int R, int C,
                                        const float* __restrict__ s, bf16* __restrict__ d)
{
    int l = i / (R * C);
    int rem = i - l * R * C;
    int k = rem / C;
    int n = rem - k * C;
    int dst = ((n >> 4) * (R >> 5) + (k >> 5)) * 512 + ((k >> 3) & 3) * 128 + (n & 15) * 8 + (k & 7);
    d[(size_t)l * R * C + dst] = f2b(s[i]);
}

__global__ void transpose_all(const float* __restrict__ p0, const float* __restrict__ p1,
                              const float* __restrict__ p2, const float* __restrict__ p3,
                              const float* __restrict__ p4, const float* __restrict__ p5,
                              const float* __restrict__ p6, const float* __restrict__ p7,
                              bf16* d0, bf16* d1, bf16* d2, bf16* d3,
                              bf16* d4, bf16* d5, bf16* d6, bf16* d7)
{
    int i = blockIdx.x * 256 + threadIdx.x;
    const int S0 = INZ * CZ;            // ee_w1  212992 (R=1664,C=128)
    const int S1 = CZ * CZ;             // ee_w2
    const int S2 = CZ * CZ;             // ee_w3
    const int S3 = NL * CZ * CZ;        // fc_w1
    const int S4 = NL * CZ * WN;        // fc_w2  851968 (R=128,C=1664)
    const int S5 = NL * 384 * CZ;       // eu_w1  (R=384,C=128)
    const int S6 = NL * CZ * CZ;        // eu_w2
    const int S7 = NL * CZ * CZ;        // eu_w3
    if (i < S0) { fragseg(i, INZ, CZ, p0, d0); return; } i -= S0;
    if (i < S1) { fragseg(i, CZ, CZ, p1, d1); return; }  i -= S1;
    if (i < S2) { fragseg(i, CZ, CZ, p2, d2); return; }  i -= S2;
    if (i < S3) { fragseg(i, CZ, CZ, p3, d3); return; }  i -= S3;
    if (i < S4) { fragseg(i, CZ, WN, p4, d4); return; }  i -= S4;
    if (i < S5) { fragseg(i, 384, CZ, p5, d5); return; } i -= S5;
    if (i < S6) { fragseg(i, CZ, CZ, p6, d6); return; }  i -= S6;
    if (i < S7) { fragseg(i, CZ, CZ, p7, d7); return; }
}

__global__ __launch_bounds__(64)
void node_embed(const float* __restrict__ node_raw, const float* __restrict__ ne_ws,
                const float* __restrict__ ne_wv, float* __restrict__ xs, float* __restrict__ xv)
{
    int n = blockIdx.x, t = threadIdx.x;
    const float* nr = node_raw + (size_t)n * NRDIM;
    if (t < 32) {
        float acc = 0.f;
        for (int i = 0; i < INS; i++) acc += nr[i] * ne_ws[i * CS + t];
        xs[n * CS + t] = acc;
    } else if (t < 56) {
        int t2 = t - 32, j = t2 / 3, x = t2 - 3 * (t2 / 3);
        float acc = 0.f;
        for (int i = 0; i < INV; i++) acc += nr[INS + i * 3 + x] * ne_wv[i * CV + j];
        xv[n * 24 + t2] = acc;
    }
}

__global__ void count_src(const int* __restrict__ ei, int* __restrict__ cnt)
{
    int e = blockIdx.x * 256 + threadIdx.x;
    if (e < NE) atomicAdd(&cnt[ei[NE + e]], 1);
}

// add agg + batchnorm stats + apply.  40 blocks.
__global__ __launch_bounds__(256)
void bnfused(float* __restrict__ xs, float* __restrict__ xv,
             const float* __restrict__ ags, const float* __restrict__ agv,
             const float* __restrict__ g, const float* __restrict__ b,
             const float* __restrict__ vg)
{
    __shared__ float red[8];
    __shared__ float stat[2];
    int c = blockIdx.x, t = threadIdx.x;
    if (c < 32) {
        float s = 0.f, s2 = 0.f;
        for (int n = t; n < NN; n += 256) {
            float v = xs[n * CS + c] + ags[n * CS + c];
            s += v; s2 += v * v;
        }
        for (int o = 32; o > 0; o >>= 1) { s += __shfl_down(s, o); s2 += __shfl_down(s2, o); }
        int w = t >> 6;
        if ((t & 63) == 0) { red[w * 2] = s; red[w * 2 + 1] = s2; }
        __syncthreads();
        if (t == 0) {
            float S = red[0] + red[2] + red[4] + red[6];
            float S2 = red[1] + red[3] + red[5] + red[7];
            float mean = S * (1.f / NN);
            float var = S2 * (1.f / NN) - mean * mean;
            stat[0] = mean;
            stat[1] = rsqrtf(var + 1e-5f);
        }
        __syncthreads();
        float mean = stat[0], rstd = stat[1], gg = g[c], bb = b[c];
        for (int n = t; n < NN; n += 256) {
            int ix = n * CS + c;
            float v = xs[ix] + ags[ix];
            xs[ix] = (v - mean) * rstd * gg + bb;
        }
    } else {
        int c2 = c - 32;
        float s = 0.f;
        for (int n = t; n < NN; n += 256) {
            float v0 = xv[n * 24 + c2 * 3 + 0] + agv[n * 24 + c2 * 3 + 0];
            float v1 = xv[n * 24 + c2 * 3 + 1] + agv[n * 24 + c2 * 3 + 1];
            float v2 = xv[n * 24 + c2 * 3 + 2] + agv[n * 24 + c2 * 3 + 2];
            s += v0 * v0 + v1 * v1 + v2 * v2;
        }
        for (int o = 32; o > 0; o >>= 1) s += __shfl_down(s, o);
        int w = t >> 6;
        if ((t & 63) == 0) red[w] = s;
        __syncthreads();
        if (t == 0) {
            float fn = (red[0] + red[1] + red[2] + red[3]) * (1.f / (3.f * NN));
            stat[0] = vg[c2] * rsqrtf(fn + 1e-5f);
        }
        __syncthreads();
        float scale = stat[0];
        for (int n = t; n < NN; n += 256) {
            for (int x = 0; x < 3; x++) {
                int ix = n * 24 + c2 * 3 + x;
                xv[ix] = (xv[ix] + agv[ix]) * scale;
            }
        }
    }
}

// a[n,128] = xs[n,:] @ eu_lin[l]
__global__ __launch_bounds__(128)
void lin_a(const float* __restrict__ xs, const float* __restrict__ eu_lin_l,
           bf16* __restrict__ a_b)
{
    __shared__ float sxs[32];
    int n = blockIdx.x, t = threadIdx.x;
    if (t < 32) sxs[t] = xs[n * CS + t];
    __syncthreads();
    float acc = 0.f;
    for (int c = 0; c < 32; c++) acc += sxs[c] * eu_lin_l[c * CZ + t];
    a_b[(size_t)n * CZ + t] = f2b(acc);
}

__global__ __launch_bounds__(128)
void final_out(const float* __restrict__ xs, const float* __restrict__ xv,
               const float* __restrict__ rot,
               const float* __restrict__ mu_w, const float* __restrict__ mu_b,
               const float* __restrict__ lv_w, const float* __restrict__ lv_b,
               float* __restrict__ out)
{
    __shared__ float feat[56];
    int n = blockIdx.x, t = threadIdx.x;
    if (t < 32) feat[t] = xs[n * CS + t];
    else if (t < 56) {
        int t2 = t - 32, c = t2 / 3, y = t2 - 3 * (t2 / 3);
        float acc = 0.f;
        for (int x = 0; x < 3; x++)
            acc += rot[n * 9 + x * 3 + y] * xv[n * 24 + c * 3 + x];
        feat[t] = acc;
    }
    __syncthreads();
    float mu = mu_b[t], lv = lv_b[t];
    for (int d = 0; d < 56; d++) {
        float f = feat[d];
        mu += f * mu_w[d * 128 + t];
        lv += f * lv_w[d * 128 + t];
    }
    out[(size_t)n * 128 + t] = mu;
    out[(size_t)NN * 128 + (size_t)n * 128 + t] = lv;
}

// ---------------------------------------------------------------------------
extern "C" void kernel_launch(void* const* d_in, const int* in_sizes, int n_in,
                              void* d_out, int out_size, void* d_ws, size_t ws_size,
                              hipStream_t stream)
{
    (void)in_sizes; (void)n_in; (void)out_size; (void)ws_size;
    const float* node_raw  = (const float*)d_in[0];
    const float* edge_raw  = (const float*)d_in[1];
    const float* edge_vecs = (const float*)d_in[2];
    const float* rot       = (const float*)d_in[3];
    const int*   ei        = (const int*  )d_in[4];
    const float* ee_w1 = (const float*)d_in[5];
    const float* ee_b1 = (const float*)d_in[6];
    const float* ee_w2 = (const float*)d_in[7];
    const float* ee_b2 = (const float*)d_in[8];
    const float* ee_w3 = (const float*)d_in[9];
    const float* ee_b3 = (const float*)d_in[10];
    const float* ee_ln_g = (const float*)d_in[11];
    const float* ee_ln_b = (const float*)d_in[12];
    const float* ne_ws = (const float*)d_in[13];
    const float* ne_wv = (const float*)d_in[14];
    const float* fc_w1 = (const float*)d_in[15];
    const float* fc_b1 = (const float*)d_in[16];
    const float* fc_w2 = (const float*)d_in[17];
    const float* fc_b2 = (const float*)d_in[18];
    const float* bn_g  = (const float*)d_in[19];
    const float* bn_b  = (const float*)d_in[20];
    const float* bn_vg = (const float*)d_in[21];
    const float* eu_lin = (const float*)d_in[22];
    const float* eu_w1 = (const float*)d_in[23];
    const float* eu_b1 = (const float*)d_in[24];
    const float* eu_w2 = (const float*)d_in[25];
    const float* eu_b2 = (const float*)d_in[26];
    const float* eu_w3 = (const float*)d_in[27];
    const float* eu_b3 = (const float*)d_in[28];
    const float* eu_ln_g = (const float*)d_in[29];
    const float* eu_ln_b = (const float*)d_in[30];
    const float* mu_w = (const float*)d_in[31];
    const float* mu_b = (const float*)d_in[32];
    const float* lv_w = (const float*)d_in[33];
    const float* lv_b = (const float*)d_in[34];

    char* ws = (char*)d_ws;
    size_t off = 0;
    auto alloc = [&](size_t bytes) -> void* {
        void* p = ws + off;
        off += (bytes + 255) & ~(size_t)255;
        return p;
    };
    bf16*  ef_b  = (bf16*) alloc((size_t)NE * CZ * 2);     // residual stream
    bf16*  buf_a = (bf16*) alloc((size_t)NE * CZ * 2);
    float* xs    = (float*)alloc((size_t)NN * CS * 4);
    float* xv    = (float*)alloc((size_t)NN * 24 * 4);
    float* ags   = (float*)alloc((size_t)NN * CS * 4);
    float* agv   = (float*)alloc((size_t)NN * 24 * 4);
    int*   cnti  = (int*)  alloc((size_t)NN * 4);
    float* icnt  = (float*)alloc((size_t)NN * 4);
    bf16*  a_b   = (bf16*) alloc((size_t)NN * CZ * 2);
    float* tp_s  = (float*)alloc((size_t)NE * 32 * 4);
    float* tp_v  = (float*)alloc((size_t)NE * 24 * 4 + 64);   // +pad for lane 56-63 reads
    int*   perm  = (int*)  alloc((size_t)NE * 4);
    int*   row_start = (int*)alloc((size_t)(NN + 1) * 4);
    int*   fillpos   = (int*)alloc((size_t)NN * 4);
    bf16* ee_w1t = (bf16*)alloc((size_t)INZ * CZ * 2);
    bf16* ee_w2t = (bf16*)alloc((size_t)CZ * CZ * 2);
    bf16* ee_w3t = (bf16*)alloc((size_t)CZ * CZ * 2);
    bf16* fc_w1t = (bf16*)alloc((size_t)NL * CZ * CZ * 2);
    bf16* fc_w2t = (bf16*)alloc((size_t)NL * WN * CZ * 2);
    bf16* eu_w1t = (bf16*)alloc((size_t)NL * 384 * CZ * 2);
    bf16* eu_w2t = (bf16*)alloc((size_t)NL * CZ * CZ * 2);
    bf16* eu_w3t = (bf16*)alloc((size_t)NL * CZ * CZ * 2);

    const int TRN = INZ*CZ + 2*CZ*CZ + NL*CZ*CZ + NL*CZ*WN + NL*384*CZ + 2*NL*CZ*CZ;
    transpose_all<<<(TRN + 255) / 256, 256, 0, stream>>>(
        ee_w1, ee_w2, ee_w3, fc_w1, fc_w2, eu_w1, eu_w2, eu_w3,
        ee_w1t, ee_w2t, ee_w3t, fc_w1t, fc_w2t, eu_w1t, eu_w2t, eu_w3t);

    node_embed<<<NN, 64, 0, stream>>>(node_raw, ne_ws, ne_wv, xs, xv);
    hipMemsetAsync(cnti, 0, NN * 4, stream);
    count_src<<<NE / 256, 256, 0, stream>>>(ei, cnti);
    scan_csr<<<1, 1024, 0, stream>>>(cnti, row_start, fillpos, icnt);
    fill_perm<<<NE / 256, 256, 0, stream>>>(ei, fillpos, perm);

    const int GE = NE / 64;   // 480
    // edge embedding: ee1 (K=1664 fp32 A) then fused ee2+ee3+LN
    gemm64<1, 1, 0><<<GE, 256, 0, stream>>>(edge_raw, ee_w1t, ee_b1, buf_a, NE, INZ, nullptr, nullptr, nullptr);
    mlp2<0><<<GE, 256, 0, stream>>>(buf_a, ee_w2t, ee_b2, ee_w3t, ee_b3, ee_ln_g, ee_ln_b, ef_b);

    for (int l = 0; l < NL; l++) {
        fc2_tp<<<NE / 64, 256, 0, stream>>>(
            ef_b, fc_w1t + (size_t)l * CZ * CZ, fc_b1 + l * CZ,
            fc_w2t + (size_t)l * WN * CZ, fc_b2 + l * WN,
            ei, edge_vecs, xs, xv, tp_s, tp_v);
        aggregate<<<NN, 64, 0, stream>>>(tp_s, tp_v, perm, row_start, icnt, ags, agv);
        bnfused<<<40, 256, 0, stream>>>(xs, xv, ags, agv,
                                        bn_g + l * CS, bn_b + l * CS, bn_vg + l * CV);
        lin_a<<<NN, 128, 0, stream>>>(xs, eu_lin + (size_t)l * CS * CZ, a_b);
        gemm64<1, 0, 1><<<GE, 256, 0, stream>>>(
            nullptr, eu_w1t + (size_t)l * 384 * CZ, eu_b1 + l * CZ, buf_a, NE, 384, a_b, ef_b, ei);
        mlp2<1><<<GE, 256, 0, stream>>>(buf_a, eu_w2t + (size_t)l * CZ * CZ, eu_b2 + l * CZ,
                                        eu_w3t + (size_t)l * CZ * CZ, eu_b3 + l * CZ,
                                        eu_ln_g + l * CZ, eu_ln_b + l * CZ, ef_b);
    }

    final_out<<<NN, 128, 0, stream>>>(xs, xv, rot, mu_w, mu_b, lv_w, lv_b, (float*)d_out);
}

// Round 4
// 877.417 us; speedup vs baseline: 1.3752x; 1.0789x over previous
//
#include <hip/hip_runtime.h>
#include <hip/hip_bf16.h>

typedef __hip_bfloat16 bf16;
typedef __attribute__((ext_vector_type(8))) short s16x8;   // 8 bf16 (4 VGPRs) MFMA frag
typedef __attribute__((ext_vector_type(4))) float f32x4;   // MFMA accumulator

#define NN 1024      // nodes
#define NE 30720     // edges
#define CS 32
#define CV 8
#define CZ 128
#define INS 28
#define INV 37
#define NRDIM 139    // 28 + 3*37
#define INZ 1664
#define WN 1664      // WEIGHT_NUMEL
#define NL 4

__device__ __forceinline__ float b2f(bf16 x) { return __bfloat162float(x); }
__device__ __forceinline__ bf16 f2b(float x) { return __float2bfloat16(x); }

// ---------------------------------------------------------------------------
// All weight matrices are stored FRAGMENT-LINEAR: for a [R rows k][C cols n]
// matrix, element (k,n) lives at ((n>>4)*(R/32) + (k>>5))*512 + ((k>>3)&3)*128
// + (n&15)*8 + (k&7).  A wave's MFMA B-fragment load for (nt=n>>4, kk=k>>5)
// is then ONE contiguous 1 KB load at base + lane*16.
// ---------------------------------------------------------------------------

// Skinny MFMA GEMM, N=128 fixed (now only used for ee1, K=1664 fp32-A).
template<int RELU, int AF32>
__global__ __launch_bounds__(256)
void gemm64(const void* __restrict__ Ap, const bf16* __restrict__ Bf,
            const float* __restrict__ bias, bf16* __restrict__ Cp,
            int M, int K)
{
    __shared__ __align__(16) bf16 la[64 * 40];
    const int bm = blockIdx.x * 64;
    const int tid = threadIdx.x;
    const int lane = tid & 63;
    const int wv = tid >> 6;
    const int lr = tid >> 1;
    const int lc = (tid & 1) * 16;
    const int l15 = lane & 15;
    const int quad = lane >> 4;
    const int K32 = K >> 5;
    f32x4 acc[4][2] = {};
    const bf16*  ga16 = (const bf16*) Ap + (size_t)(bm + lr) * K + lc;
    const float* ga32 = (const float*)Ap + (size_t)(bm + lr) * K + lc;
    for (int k0 = 0; k0 < K; k0 += 32) {
        union { bf16 h[16]; float4 q[2]; } pa;
        if (tid < 128) {
            if (AF32) {
                float4 f0 = *(const float4*)(ga32 + k0);
                float4 f1 = *(const float4*)(ga32 + k0 + 4);
                float4 f2 = *(const float4*)(ga32 + k0 + 8);
                float4 f3 = *(const float4*)(ga32 + k0 + 12);
                pa.h[0]=f2b(f0.x); pa.h[1]=f2b(f0.y); pa.h[2]=f2b(f0.z); pa.h[3]=f2b(f0.w);
                pa.h[4]=f2b(f1.x); pa.h[5]=f2b(f1.y); pa.h[6]=f2b(f1.z); pa.h[7]=f2b(f1.w);
                pa.h[8]=f2b(f2.x); pa.h[9]=f2b(f2.y); pa.h[10]=f2b(f2.z); pa.h[11]=f2b(f2.w);
                pa.h[12]=f2b(f3.x); pa.h[13]=f2b(f3.y); pa.h[14]=f2b(f3.z); pa.h[15]=f2b(f3.w);
            } else {
                pa.q[0] = *(const float4*)(ga16 + k0);
                pa.q[1] = *(const float4*)(ga16 + k0 + 8);
            }
        }
        s16x8 bfr[2];
#pragma unroll
        for (int ni = 0; ni < 2; ni++)
            bfr[ni] = *(const s16x8*)(Bf + (size_t)(((wv * 2 + ni) * K32 + (k0 >> 5)) * 512) + lane * 8);
        __syncthreads();
        if (tid < 128) {
            *(float4*)&la[lr * 40 + lc]     = pa.q[0];
            *(float4*)&la[lr * 40 + lc + 8] = pa.q[1];
        }
        __syncthreads();
        s16x8 af[4];
#pragma unroll
        for (int mi = 0; mi < 4; mi++)
            af[mi] = *(const s16x8*)&la[(mi * 16 + l15) * 40 + quad * 8];
#pragma unroll
        for (int mi = 0; mi < 4; mi++)
#pragma unroll
            for (int ni = 0; ni < 2; ni++)
                acc[mi][ni] = __builtin_amdgcn_mfma_f32_16x16x32_bf16(af[mi], bfr[ni], acc[mi][ni], 0, 0, 0);
    }
#pragma unroll
    for (int ni = 0; ni < 2; ni++) {
        const int col = wv * 32 + ni * 16 + l15;
        const float bv = bias[col];
#pragma unroll
        for (int mi = 0; mi < 4; mi++) {
            const int row0 = bm + mi * 16 + quad * 4;
#pragma unroll
            for (int r = 0; r < 4; r++) {
                float v = acc[mi][ni][r] + bv;
                if (RELU) v = fmaxf(v, 0.f);
                Cp[(size_t)(row0 + r) * CZ + col] = f2b(v);
            }
        }
    }
}

// ---------------------------------------------------------------------------
// ee MLP tail: u2 = relu(A@W2+b2); u3 = u2@W3+b3; LN -> efb (bf16).
// ---------------------------------------------------------------------------
__global__ __launch_bounds__(256)
void mlp2(const bf16* __restrict__ A,
          const bf16* __restrict__ w2f, const float* __restrict__ b2,
          const bf16* __restrict__ w3f, const float* __restrict__ b3,
          const float* __restrict__ g, const float* __restrict__ bb,
          bf16* efb)
{
    __shared__ __align__(16) bf16 s_a[64 * 136];
    __shared__ __align__(16) bf16 s_u[64 * 136];
    __shared__ float s_o[64 * 132];
    const int bm = blockIdx.x * 64;
    const int t = threadIdx.x;
    const int lane = t & 63;
    const int wv = t >> 6;
    const int l15 = lane & 15;
    const int quad = lane >> 4;
    {   // stage A tile 64x128
        int r = t >> 2, c0 = (t & 3) * 32;
        const float4* s4 = (const float4*)(A + (size_t)(bm + r) * CZ + c0);
        float4* d4 = (float4*)&s_a[r * 136 + c0];
        d4[0] = s4[0]; d4[1] = s4[1]; d4[2] = s4[2]; d4[3] = s4[3];
    }
    __syncthreads();
    s16x8 af[4][4];
#pragma unroll
    for (int mi = 0; mi < 4; mi++)
#pragma unroll
        for (int kk = 0; kk < 4; kk++)
            af[mi][kk] = *(const s16x8*)&s_a[(mi * 16 + l15) * 136 + kk * 32 + quad * 8];
#pragma unroll
    for (int s = 0; s < 2; s++) {
        int n = wv * 32 + s * 16 + l15;
        f32x4 acc[4] = {};
#pragma unroll
        for (int kk = 0; kk < 4; kk++) {
            s16x8 bfr = *(const s16x8*)(w2f + (size_t)(((wv * 2 + s) * 4 + kk) * 512) + lane * 8);
#pragma unroll
            for (int mi = 0; mi < 4; mi++)
                acc[mi] = __builtin_amdgcn_mfma_f32_16x16x32_bf16(af[mi][kk], bfr, acc[mi], 0, 0, 0);
        }
        float bv = b2[n];
#pragma unroll
        for (int mi = 0; mi < 4; mi++)
#pragma unroll
            for (int r = 0; r < 4; r++)
                s_u[(mi * 16 + quad * 4 + r) * 136 + n] = f2b(fmaxf(acc[mi][r] + bv, 0.f));
    }
    __syncthreads();
#pragma unroll
    for (int mi = 0; mi < 4; mi++)
#pragma unroll
        for (int kk = 0; kk < 4; kk++)
            af[mi][kk] = *(const s16x8*)&s_u[(mi * 16 + l15) * 136 + kk * 32 + quad * 8];
#pragma unroll
    for (int s = 0; s < 2; s++) {
        int n = wv * 32 + s * 16 + l15;
        f32x4 acc[4] = {};
#pragma unroll
        for (int kk = 0; kk < 4; kk++) {
            s16x8 bfr = *(const s16x8*)(w3f + (size_t)(((wv * 2 + s) * 4 + kk) * 512) + lane * 8);
#pragma unroll
            for (int mi = 0; mi < 4; mi++)
                acc[mi] = __builtin_amdgcn_mfma_f32_16x16x32_bf16(af[mi][kk], bfr, acc[mi], 0, 0, 0);
        }
        float bv = b3[n];
#pragma unroll
        for (int mi = 0; mi < 4; mi++)
#pragma unroll
            for (int r = 0; r < 4; r++)
                s_o[(mi * 16 + quad * 4 + r) * 132 + n] = acc[mi][r] + bv;
    }
    __syncthreads();
    {   // LN per row: 4 lanes per row, 32 cols each
        int row = wv * 16 + (lane >> 2);
        int q = lane & 3;
        int col0 = q * 32;
        size_t gbase = (size_t)(bm + row) * CZ;
        float s = 0.f, s2 = 0.f;
        for (int i = 0; i < 32; i++) {
            float x = s_o[row * 132 + col0 + i];
            s += x; s2 += x * x;
        }
        s  += __shfl_xor(s, 1);  s2 += __shfl_xor(s2, 1);
        s  += __shfl_xor(s, 2);  s2 += __shfl_xor(s2, 2);
        float mean = s * (1.f / 128.f);
        float var  = s2 * (1.f / 128.f) - mean * mean;
        float rstd = rsqrtf(var + 1e-5f);
        for (int i = 0; i < 32; i++) {
            int col = col0 + i;
            float x = s_o[row * 132 + col];
            efb[gbase + col] = f2b((x - mean) * rstd * g[col] + bb[col]);
        }
    }
}

// ---------------------------------------------------------------------------
// Fused EdgeUpdate: u1 = relu(ef@W1c + ad[dst] + as[src] + b1);
// u2 = relu(u1@W2+b2); u3 = u2@W3+b3; efb = LN(ef + u3).
// Replaces lin_a + gemm64<GATHER,K=384> + mlp2<RESID>: the a[dst]/a[src]
// contributions are folded per-node (ad = xs@(eu_lin@W1a) etc), so the
// per-edge K drops 384->128, the buf_a 15.7 MB round-trip disappears, and
// ef is staged ONCE (GEMM input + LN residual).  LDS region s_go is reused
// gather(f32) -> u2(bf16) -> s_o(f32); total 68.6 KB -> 2 blocks/CU.
// ---------------------------------------------------------------------------
__global__ __launch_bounds__(256)
void eu_fused(bf16* __restrict__ efb,
              const float* __restrict__ adg, const float* __restrict__ asg,
              const int* __restrict__ ei,
              const bf16* __restrict__ w1cf, const float* __restrict__ b1,
              const bf16* __restrict__ w2f, const float* __restrict__ b2,
              const bf16* __restrict__ w3f, const float* __restrict__ b3,
              const float* __restrict__ g, const float* __restrict__ bb)
{
    __shared__ __align__(16) bf16 s_a[64 * 136];     // ef tile (GEMM A + resid)
    __shared__ __align__(16) bf16 s_u1[64 * 136];
    __shared__ __align__(16) float s_go[64 * 132];   // gather -> u2 -> s_o
    bf16* const s_u2 = (bf16*)s_go;
    const int bm = blockIdx.x * 64;
    const int t = threadIdx.x;
    const int lane = t & 63;
    const int wv = t >> 6;
    const int l15 = lane & 15;
    const int quad = lane >> 4;
    {   // stage ef tile + gather g = ad[dst] + as[src]
        int r = t >> 2, c0 = (t & 3) * 32;
        const float4* s4 = (const float4*)(efb + (size_t)(bm + r) * CZ + c0);
        float4* d4 = (float4*)&s_a[r * 136 + c0];
        d4[0] = s4[0]; d4[1] = s4[1]; d4[2] = s4[2]; d4[3] = s4[3];
        int dst = ei[bm + r], src = ei[NE + bm + r];
        const float4* pd = (const float4*)(adg + (size_t)dst * CZ + c0);
        const float4* ps = (const float4*)(asg + (size_t)src * CZ + c0);
        float4* dg = (float4*)&s_go[r * 132 + c0];
#pragma unroll
        for (int k = 0; k < 8; k++) {
            float4 va = pd[k], vb = ps[k];
            dg[k] = make_float4(va.x + vb.x, va.y + vb.y, va.z + vb.z, va.w + vb.w);
        }
    }
    __syncthreads();
    // phase A: u1 = relu(ef@W1c + g + b1)
    {
        s16x8 af[4][4];
#pragma unroll
        for (int mi = 0; mi < 4; mi++)
#pragma unroll
            for (int kk = 0; kk < 4; kk++)
                af[mi][kk] = *(const s16x8*)&s_a[(mi * 16 + l15) * 136 + kk * 32 + quad * 8];
#pragma unroll
        for (int s = 0; s < 2; s++) {
            int n = wv * 32 + s * 16 + l15;
            f32x4 acc[4] = {};
#pragma unroll
            for (int kk = 0; kk < 4; kk++) {
                s16x8 bfr = *(const s16x8*)(w1cf + (size_t)(((wv * 2 + s) * 4 + kk) * 512) + lane * 8);
#pragma unroll
                for (int mi = 0; mi < 4; mi++)
                    acc[mi] = __builtin_amdgcn_mfma_f32_16x16x32_bf16(af[mi][kk], bfr, acc[mi], 0, 0, 0);
            }
            float bv = b1[n];
#pragma unroll
            for (int mi = 0; mi < 4; mi++)
#pragma unroll
                for (int r = 0; r < 4; r++) {
                    int e = mi * 16 + quad * 4 + r;
                    s_u1[e * 136 + n] = f2b(fmaxf(acc[mi][r] + bv + s_go[e * 132 + n], 0.f));
                }
        }
    }
    __syncthreads();
    // phase B: u2 = relu(u1@W2 + b2) -> s_u2 (aliases s_go; g is dead)
    {
        s16x8 af[4][4];
#pragma unroll
        for (int mi = 0; mi < 4; mi++)
#pragma unroll
            for (int kk = 0; kk < 4; kk++)
                af[mi][kk] = *(const s16x8*)&s_u1[(mi * 16 + l15) * 136 + kk * 32 + quad * 8];
#pragma unroll
        for (int s = 0; s < 2; s++) {
            int n = wv * 32 + s * 16 + l15;
            f32x4 acc[4] = {};
#pragma unroll
            for (int kk = 0; kk < 4; kk++) {
                s16x8 bfr = *(const s16x8*)(w2f + (size_t)(((wv * 2 + s) * 4 + kk) * 512) + lane * 8);
#pragma unroll
                for (int mi = 0; mi < 4; mi++)
                    acc[mi] = __builtin_amdgcn_mfma_f32_16x16x32_bf16(af[mi][kk], bfr, acc[mi], 0, 0, 0);
            }
            float bv = b2[n];
#pragma unroll
            for (int mi = 0; mi < 4; mi++)
#pragma unroll
                for (int r = 0; r < 4; r++)
                    s_u2[(mi * 16 + quad * 4 + r) * 136 + n] = f2b(fmaxf(acc[mi][r] + bv, 0.f));
        }
    }
    __syncthreads();
    // phase C: x = u2@W3 + b3 + ef (resid); then overwrite s_go with x (f32)
    {
        s16x8 af[4][4];
#pragma unroll
        for (int mi = 0; mi < 4; mi++)
#pragma unroll
            for (int kk = 0; kk < 4; kk++)
                af[mi][kk] = *(const s16x8*)&s_u2[(mi * 16 + l15) * 136 + kk * 32 + quad * 8];
        __syncthreads();   // all u2 reads done before s_go is overwritten
#pragma unroll
        for (int s = 0; s < 2; s++) {
            int n = wv * 32 + s * 16 + l15;
            f32x4 acc[4] = {};
#pragma unroll
            for (int kk = 0; kk < 4; kk++) {
                s16x8 bfr = *(const s16x8*)(w3f + (size_t)(((wv * 2 + s) * 4 + kk) * 512) + lane * 8);
#pragma unroll
                for (int mi = 0; mi < 4; mi++)
                    acc[mi] = __builtin_amdgcn_mfma_f32_16x16x32_bf16(af[mi][kk], bfr, acc[mi], 0, 0, 0);
            }
            float bv = b3[n];
#pragma unroll
            for (int mi = 0; mi < 4; mi++)
#pragma unroll
                for (int r = 0; r < 4; r++) {
                    int e = mi * 16 + quad * 4 + r;
                    s_go[e * 132 + n] = acc[mi][r] + bv + b2f(s_a[e * 136 + n]);
                }
        }
    }
    __syncthreads();
    {   // LN per row (resid already folded into x)
        int row = wv * 16 + (lane >> 2);
        int q = lane & 3;
        int col0 = q * 32;
        size_t gbase = (size_t)(bm + row) * CZ;
        float s = 0.f, s2 = 0.f;
        for (int i = 0; i < 32; i++) {
            float x = s_go[row * 132 + col0 + i];
            s += x; s2 += x * x;
        }
        s  += __shfl_xor(s, 1);  s2 += __shfl_xor(s2, 1);
        s  += __shfl_xor(s, 2);  s2 += __shfl_xor(s2, 2);
        float mean = s * (1.f / 128.f);
        float var  = s2 * (1.f / 128.f) - mean * mean;
        float rstd = rsqrtf(var + 1e-5f);
        for (int i = 0; i < 32; i++) {
            int col = col0 + i;
            float x = s_go[row * 132 + col];
            efb[gbase + col] = f2b((x - mean) * rstd * g[col] + bb[col]);
        }
    }
}

// ---------------------------------------------------------------------------
// Fused fc1 + fc2 + tensor product.  Block = 64 edges (grid 480). Unchanged.
// ---------------------------------------------------------------------------
__global__ __launch_bounds__(256, 2)
void fc2_tp(const bf16* __restrict__ ef,
            const bf16* __restrict__ w1f, const float* __restrict__ b1,
            const bf16* __restrict__ w2f, const float* __restrict__ b2,
            const int* __restrict__ ei, const float* __restrict__ edge_vecs,
            const float* __restrict__ xs, const float* __restrict__ xv,
            float* __restrict__ tp_s, float* __restrict__ tp_v)
{
    __shared__ __align__(16) bf16 s_a[64 * 136];
    __shared__ __align__(16) bf16 s_h[64 * 136];
    __shared__ __align__(16) float s_xsT[32][64];
    __shared__ __align__(16) float s_xvT[24][64];
    __shared__ __align__(16) float s_crT[24][64];
    __shared__ __align__(16) float s_y4T[8][64];
    __shared__ __align__(16) float s_b2[WN];
    __shared__ float s_shv[64][3];
    __shared__ int s_dst[64];
    __shared__ float s_os[64][32];
    __shared__ float s_ov[64][24];
    const int be = blockIdx.x * 64;
    const int t = threadIdx.x;
    const int lane = t & 63;
    const int wv = t >> 6;
    const int l15 = lane & 15;
    const int quad = lane >> 4;
    const int q4 = quad * 4;

    if (t < 64) {
        int e = be + t;
        s_dst[t] = ei[e];
        float vx = edge_vecs[e * 3 + 0];
        float vy = edge_vecs[e * 3 + 1];
        float vz = edge_vecs[e * 3 + 2];
        float sc = 1.7320508075688772f / (sqrtf(vx * vx + vy * vy + vz * vz) + 1e-8f);
        s_shv[t][0] = vx * sc; s_shv[t][1] = vy * sc; s_shv[t][2] = vz * sc;
    }
    for (int i = t; i < 64 * 32; i += 256) ((float*)s_os)[i] = 0.f;
    for (int i = t; i < 64 * 24; i += 256) ((float*)s_ov)[i] = 0.f;
    for (int i = t; i < WN; i += 256) s_b2[i] = b2[i];
    {   // stage ef tile 64x128
        int r = t >> 2, c0 = (t & 3) * 32;
        const float4* s4 = (const float4*)(ef + (size_t)(be + r) * CZ + c0);
        float4* d4 = (float4*)&s_a[r * 136 + c0];
        d4[0] = s4[0]; d4[1] = s4[1]; d4[2] = s4[2]; d4[3] = s4[3];
    }
    __syncthreads();
    for (int i = t; i < 64 * 32; i += 256) { int e = i & 63, c = i >> 6; s_xsT[c][e] = xs[s_dst[e] * CS + c]; }
    for (int i = t; i < 64 * 24; i += 256) { int e = i & 63, c = i >> 6; s_xvT[c][e] = xv[s_dst[e] * 24 + c]; }
    __syncthreads();
    for (int i2 = t; i2 < 512; i2 += 256) {
        int e = i2 & 63, i = i2 >> 6;
        float h0 = s_shv[e][0], h1 = s_shv[e][1], h2 = s_shv[e][2];
        float x0 = s_xvT[i * 3 + 0][e], x1 = s_xvT[i * 3 + 1][e], x2 = s_xvT[i * 3 + 2][e];
        s_y4T[i][e] = 1.1547005383792515f * (x0 * h0 + x1 * h1 + x2 * h2);
        s_crT[i * 3 + 0][e] = 0.7071067811865476f * (x1 * h2 - x2 * h1);
        s_crT[i * 3 + 1][e] = 0.7071067811865476f * (x2 * h0 - x0 * h2);
        s_crT[i * 3 + 2][e] = 0.7071067811865476f * (x0 * h1 - x1 * h0);
    }
    // phase 1: h = relu(ef@W1+b1)
    {
        s16x8 af1[4][4];
#pragma unroll
        for (int mi = 0; mi < 4; mi++)
#pragma unroll
            for (int kk = 0; kk < 4; kk++)
                af1[mi][kk] = *(const s16x8*)&s_a[(mi * 16 + l15) * 136 + kk * 32 + quad * 8];
#pragma unroll
        for (int s = 0; s < 2; s++) {
            int n = wv * 32 + s * 16 + l15;
            f32x4 acc[4] = {};
#pragma unroll
            for (int kk = 0; kk < 4; kk++) {
                s16x8 bfr = *(const s16x8*)(w1f + (size_t)(((wv * 2 + s) * 4 + kk) * 512) + lane * 8);
#pragma unroll
                for (int mi = 0; mi < 4; mi++)
                    acc[mi] = __builtin_amdgcn_mfma_f32_16x16x32_bf16(af1[mi][kk], bfr, acc[mi], 0, 0, 0);
            }
            float bv = b1[n];
#pragma unroll
            for (int mi = 0; mi < 4; mi++)
#pragma unroll
                for (int r = 0; r < 4; r++)
                    s_h[(mi * 16 + quad * 4 + r) * 136 + n] = f2b(fmaxf(acc[mi][r] + bv, 0.f));
        }
    }
    __syncthreads();
    // phase 2: stream w = h@W2+b2 through registers, contract immediately
    s16x8 af[4][4];
#pragma unroll
    for (int mi = 0; mi < 4; mi++)
#pragma unroll
        for (int kk = 0; kk < 4; kk++)
            af[mi][kk] = *(const s16x8*)&s_h[(mi * 16 + l15) * 136 + kk * 32 + quad * 8];
    float os[4][4] = {}, sv2[4][4] = {}, ov0[4][4] = {}, ov1[4][4] = {}, ov2[4][4] = {};
    const int ib = l15 >> 3;
    for (int nt = wv; nt < 104; nt += 4) {
        const float bv = s_b2[nt * 16 + l15];
        const bf16* wb = w2f + (size_t)(nt * 4) * 512 + lane * 8;
        s16x8 bfr[4];
#pragma unroll
        for (int kk = 0; kk < 4; kk++)
            bfr[kk] = *(const s16x8*)(wb + kk * 512);
        f32x4 ac[4] = {};
#pragma unroll
        for (int kk = 0; kk < 4; kk++)
#pragma unroll
            for (int mi = 0; mi < 4; mi++)
                ac[mi] = __builtin_amdgcn_mfma_f32_16x16x32_bf16(af[mi][kk], bfr[kk], ac[mi], 0, 0, 0);
        if (nt < 64) {
            const int i = nt >> 1;
#pragma unroll
            for (int mi = 0; mi < 4; mi++) {
                float4 f = *(const float4*)&s_xsT[i][mi * 16 + q4];
                os[mi][0] += (ac[mi][0] + bv) * f.x; os[mi][1] += (ac[mi][1] + bv) * f.y;
                os[mi][2] += (ac[mi][2] + bv) * f.z; os[mi][3] += (ac[mi][3] + bv) * f.w;
            }
        } else if (nt < 80) {
            const int i = (nt - 64) * 2 + ib;
#pragma unroll
            for (int mi = 0; mi < 4; mi++) {
                float4 f = *(const float4*)&s_xsT[i][mi * 16 + q4];
                sv2[mi][0] += (ac[mi][0] + bv) * f.x; sv2[mi][1] += (ac[mi][1] + bv) * f.y;
                sv2[mi][2] += (ac[mi][2] + bv) * f.z; sv2[mi][3] += (ac[mi][3] + bv) * f.w;
            }
        } else if (nt < 84) {
            const int i0 = ((nt - 80) * 2 + ib) * 3;
#pragma unroll
            for (int mi = 0; mi < 4; mi++) {
                float4 f0 = *(const float4*)&s_xvT[i0 + 0][mi * 16 + q4];
                float4 f1 = *(const float4*)&s_xvT[i0 + 1][mi * 16 + q4];
                float4 f2 = *(const float4*)&s_xvT[i0 + 2][mi * 16 + q4];
                float w0 = ac[mi][0] + bv, w1 = ac[mi][1] + bv, w2 = ac[mi][2] + bv, w3 = ac[mi][3] + bv;
                ov0[mi][0] += w0 * f0.x; ov0[mi][1] += w1 * f0.y; ov0[mi][2] += w2 * f0.z; ov0[mi][3] += w3 * f0.w;
                ov1[mi][0] += w0 * f1.x; ov1[mi][1] += w1 * f1.y; ov1[mi][2] += w2 * f1.z; ov1[mi][3] += w3 * f1.w;
                ov2[mi][0] += w0 * f2.x; ov2[mi][1] += w1 * f2.y; ov2[mi][2] += w2 * f2.z; ov2[mi][3] += w3 * f2.w;
            }
        } else if (nt < 100) {
            const int i = (nt - 84) >> 1;
#pragma unroll
            for (int mi = 0; mi < 4; mi++) {
                float4 f = *(const float4*)&s_y4T[i][mi * 16 + q4];
                os[mi][0] += (ac[mi][0] + bv) * f.x; os[mi][1] += (ac[mi][1] + bv) * f.y;
                os[mi][2] += (ac[mi][2] + bv) * f.z; os[mi][3] += (ac[mi][3] + bv) * f.w;
            }
        } else {
            const int i0 = ((nt - 100) * 2 + ib) * 3;
#pragma unroll
            for (int mi = 0; mi < 4; mi++) {
                float4 f0 = *(const float4*)&s_crT[i0 + 0][mi * 16 + q4];
                float4 f1 = *(const float4*)&s_crT[i0 + 1][mi * 16 + q4];
                float4 f2 = *(const float4*)&s_crT[i0 + 2][mi * 16 + q4];
                float w0 = ac[mi][0] + bv, w1 = ac[mi][1] + bv, w2 = ac[mi][2] + bv, w3 = ac[mi][3] + bv;
                ov0[mi][0] += w0 * f0.x; ov0[mi][1] += w1 * f0.y; ov0[mi][2] += w2 * f0.z; ov0[mi][3] += w3 * f0.w;
                ov1[mi][0] += w0 * f1.x; ov1[mi][1] += w1 * f1.y; ov1[mi][2] += w2 * f1.z; ov1[mi][3] += w3 * f1.w;
                ov2[mi][0] += w0 * f2.x; ov2[mi][1] += w1 * f2.y; ov2[mi][2] += w2 * f2.z; ov2[mi][3] += w3 * f2.w;
            }
        }
    }
    {
        const int jo = (wv & 1) * 16 + l15;
        const int jv3 = (l15 & 7) * 3;
#pragma unroll
        for (int mi = 0; mi < 4; mi++)
#pragma unroll
            for (int r = 0; r < 4; r++) {
                int e = mi * 16 + quad * 4 + r;
                atomicAdd(&s_os[e][jo], os[mi][r]);
                float sv = 0.5f * sv2[mi][r];
                atomicAdd(&s_ov[e][jv3 + 0], ov0[mi][r] + s_shv[e][0] * sv);
                atomicAdd(&s_ov[e][jv3 + 1], ov1[mi][r] + s_shv[e][1] * sv);
                atomicAdd(&s_ov[e][jv3 + 2], ov2[mi][r] + s_shv[e][2] * sv);
            }
    }
    __syncthreads();
    for (int i = t; i < 64 * 32; i += 256) {
        int e = i >> 5, d = i & 31;
        tp_s[(size_t)(be + e) * 32 + d] = s_os[e][d] * 0.125f;
    }
    for (int i = t; i < 64 * 24; i += 256) {
        int e = i / 24, d = i - e * 24;
        tp_v[(size_t)(be + e) * 24 + d] = s_ov[e][d] * 0.2041241452319315f;
    }
}

// ---------------------------------------------------------------------------
// CSR build + segment-sum gather (unchanged).
// ---------------------------------------------------------------------------
__global__ __launch_bounds__(1024)
void scan_csr(const int* __restrict__ cnt, int* __restrict__ row_start,
              int* __restrict__ fillpos, float* __restrict__ icnt)
{
    __shared__ int tmp[1024];
    int t = threadIdx.x;
    int v = cnt[t];
    tmp[t] = v;
    __syncthreads();
    for (int o = 1; o < 1024; o <<= 1) {
        int x = (t >= o) ? tmp[t - o] : 0;
        __syncthreads();
        tmp[t] += x;
        __syncthreads();
    }
    int excl = tmp[t] - v;
    row_start[t] = excl;
    fillpos[t] = excl;
    if (t == 1023) row_start[1024] = tmp[1023];
    icnt[t] = 1.0f / (float)(v > 1 ? v : 1);
}

__global__ void fill_perm(const int* __restrict__ ei, int* __restrict__ fillpos,
                          int* __restrict__ perm)
{
    int e = blockIdx.x * 256 + threadIdx.x;
    if (e < NE) {
        int s = ei[NE + e];
        int p = atomicAdd(&fillpos[s], 1);
        perm[p] = e;
    }
}

__global__ __launch_bounds__(64)
void aggregate(const float* __restrict__ tp_s, const float* __restrict__ tp_v,
               const int* __restrict__ perm, const int* __restrict__ row_start,
               const float* __restrict__ icnt,
               float* __restrict__ ags, float* __restrict__ agv)
{
    __shared__ int s_e[64];
    const int n = blockIdx.x, t = threadIdx.x;
    const int s = row_start[n], epe = row_start[n + 1];
    float acc = 0.f;
    for (int k0 = s; k0 < epe; k0 += 64) {
        int kk = k0 + t;
        s_e[t] = (kk < epe) ? perm[kk] : 0;
        __syncthreads();
        int m = epe - k0; if (m > 64) m = 64;
        for (int j = 0; j < m; j++) {
            int e = s_e[j];
            acc += (t < 32) ? tp_s[(size_t)e * 32 + t]
                            : tp_v[(size_t)e * 24 + (t - 32)];
        }
        __syncthreads();
    }
    acc *= icnt[n];
    if (t < 32) ags[n * CS + t] = acc;
    else if (t < 56) agv[n * 24 + (t - 32)] = acc;
}

// ---------------------------------------------------------------------------
// Weight repack: fragment-linear for a [R][C] matrix (leading layer dim l).
// eu_w1: only rows 256..383 (the ef part) are repacked — rows 0..255 are
// folded into per-node ad/as via fold_f.
// ---------------------------------------------------------------------------
__device__ __forceinline__ void fragseg(int i, int R, int C,
                                        const float* __restrict__ s, bf16* __restrict__ d)
{
    int l = i / (R * C);
    int rem = i - l * R * C;
    int k = rem / C;
    int n = rem - k * C;
    int dst = ((n >> 4) * (R >> 5) + (k >> 5)) * 512 + ((k >> 3) & 3) * 128 + (n & 15) * 8 + (k & 7);
    d[(size_t)l * R * C + dst] = f2b(s[i]);
}

__global__ void transpose_all(const float* __restrict__ p0, const float* __restrict__ p1,
                              const float* __restrict__ p2, const float* __restrict__ p3,
                              const float* __restrict__ p4, const float* __restrict__ p5,
                              const float* __restrict__ p6, const float* __restrict__ p7,
                              bf16* d0, bf16* d1, bf16* d2, bf16* d3,
                              bf16* d4, bf16* d5, bf16* d6, bf16* d7)
{
    int i = blockIdx.x * 256 + threadIdx.x;
    const int S0 = INZ * CZ;            // ee_w1  (R=1664,C=128)
    const int S1 = CZ * CZ;             // ee_w2
    const int S2 = CZ * CZ;             // ee_w3
    const int S3 = NL * CZ * CZ;        // fc_w1
    const int S4 = NL * CZ * WN;        // fc_w2  (R=128,C=1664)
    const int S5 = NL * 384 * CZ;       // eu_w1  (only k>=256 repacked)
    const int S6 = NL * CZ * CZ;        // eu_w2
    const int S7 = NL * CZ * CZ;        // eu_w3
    if (i < S0) { fragseg(i, INZ, CZ, p0, d0); return; } i -= S0;
    if (i < S1) { fragseg(i, CZ, CZ, p1, d1); return; }  i -= S1;
    if (i < S2) { fragseg(i, CZ, CZ, p2, d2); return; }  i -= S2;
    if (i < S3) { fragseg(i, CZ, CZ, p3, d3); return; }  i -= S3;
    if (i < S4) { fragseg(i, CZ, WN, p4, d4); return; }  i -= S4;
    if (i < S5) {
        int l = i / (384 * CZ);
        int rem = i - l * (384 * CZ);
        int k = rem / CZ, n = rem - k * CZ;
        if (k >= 256) {
            int k2 = k - 256;
            int dst = ((n >> 4) * (CZ >> 5) + (k2 >> 5)) * 512 + ((k2 >> 3) & 3) * 128 + (n & 15) * 8 + (k2 & 7);
            d5[(size_t)l * CZ * CZ + dst] = f2b(p5[i]);
        }
        return;
    } i -= S5;
    if (i < S6) { fragseg(i, CZ, CZ, p6, d6); return; }  i -= S6;
    if (i < S7) { fragseg(i, CZ, CZ, p7, d7); return; }
}

// F_d = eu_lin @ W1a, F_s = eu_lin @ W1b  (per layer, f32).  8 blocks.
__global__ __launch_bounds__(256)
void fold_f(const float* __restrict__ eu_lin, const float* __restrict__ eu_w1,
            float* __restrict__ Fw)
{
    int b = blockIdx.x, t = threadIdx.x;
    int l = b >> 1, part = b & 1;
    const float* L = eu_lin + (size_t)l * CS * CZ;
    const float* W = eu_w1 + (size_t)l * 384 * CZ + (size_t)part * CZ * CZ;
    float* out = Fw + (size_t)b * CS * CZ;
    for (int idx = t; idx < CS * CZ; idx += 256) {
        int i = idx >> 7, n = idx & 127;
        float acc = 0.f;
        for (int k = 0; k < CZ; k++)
            acc += L[i * CZ + k] * W[k * CZ + n];
        out[idx] = acc;
    }
}

// ad = xs@F_d, as = xs@F_s  (replaces lin_a; f32 out)
__global__ __launch_bounds__(128)
void adas(const float* __restrict__ xs, const float* __restrict__ Fd,
          const float* __restrict__ Fs, float* __restrict__ adg, float* __restrict__ asg)
{
    __shared__ float sxs[32];
    int n = blockIdx.x, t = threadIdx.x;
    if (t < 32) sxs[t] = xs[n * CS + t];
    __syncthreads();
    float a = 0.f, b = 0.f;
    for (int i = 0; i < 32; i++) {
        float x = sxs[i];
        a += x * Fd[i * CZ + t];
        b += x * Fs[i * CZ + t];
    }
    adg[(size_t)n * CZ + t] = a;
    asg[(size_t)n * CZ + t] = b;
}

__global__ __launch_bounds__(64)
void node_embed(const float* __restrict__ node_raw, const float* __restrict__ ne_ws,
                const float* __restrict__ ne_wv, float* __restrict__ xs, float* __restrict__ xv)
{
    int n = blockIdx.x, t = threadIdx.x;
    const float* nr = node_raw + (size_t)n * NRDIM;
    if (t < 32) {
        float acc = 0.f;
        for (int i = 0; i < INS; i++) acc += nr[i] * ne_ws[i * CS + t];
        xs[n * CS + t] = acc;
    } else if (t < 56) {
        int t2 = t - 32, j = t2 / 3, x = t2 - 3 * (t2 / 3);
        float acc = 0.f;
        for (int i = 0; i < INV; i++) acc += nr[INS + i * 3 + x] * ne_wv[i * CV + j];
        xv[n * 24 + t2] = acc;
    }
}

__global__ void count_src(const int* __restrict__ ei, int* __restrict__ cnt)
{
    int e = blockIdx.x * 256 + threadIdx.x;
    if (e < NE) atomicAdd(&cnt[ei[NE + e]], 1);
}

// add agg + batchnorm stats + apply.  40 blocks.
__global__ __launch_bounds__(256)
void bnfused(float* __restrict__ xs, float* __restrict__ xv,
             const float* __restrict__ ags, const float* __restrict__ agv,
             const float* __restrict__ g, const float* __restrict__ b,
             const float* __restrict__ vg)
{
    __shared__ float red[8];
    __shared__ float stat[2];
    int c = blockIdx.x, t = threadIdx.x;
    if (c < 32) {
        float s = 0.f, s2 = 0.f;
        for (int n = t; n < NN; n += 256) {
            float v = xs[n * CS + c] + ags[n * CS + c];
            s += v; s2 += v * v;
        }
        for (int o = 32; o > 0; o >>= 1) { s += __shfl_down(s, o); s2 += __shfl_down(s2, o); }
        int w = t >> 6;
        if ((t & 63) == 0) { red[w * 2] = s; red[w * 2 + 1] = s2; }
        __syncthreads();
        if (t == 0) {
            float S = red[0] + red[2] + red[4] + red[6];
            float S2 = red[1] + red[3] + red[5] + red[7];
            float mean = S * (1.f / NN);
            float var = S2 * (1.f / NN) - mean * mean;
            stat[0] = mean;
            stat[1] = rsqrtf(var + 1e-5f);
        }
        __syncthreads();
        float mean = stat[0], rstd = stat[1], gg = g[c], bb = b[c];
        for (int n = t; n < NN; n += 256) {
            int ix = n * CS + c;
            float v = xs[ix] + ags[ix];
            xs[ix] = (v - mean) * rstd * gg + bb;
        }
    } else {
        int c2 = c - 32;
        float s = 0.f;
        for (int n = t; n < NN; n += 256) {
            float v0 = xv[n * 24 + c2 * 3 + 0] + agv[n * 24 + c2 * 3 + 0];
            float v1 = xv[n * 24 + c2 * 3 + 1] + agv[n * 24 + c2 * 3 + 1];
            float v2 = xv[n * 24 + c2 * 3 + 2] + agv[n * 24 + c2 * 3 + 2];
            s += v0 * v0 + v1 * v1 + v2 * v2;
        }
        for (int o = 32; o > 0; o >>= 1) s += __shfl_down(s, o);
        int w = t >> 6;
        if ((t & 63) == 0) red[w] = s;
        __syncthreads();
        if (t == 0) {
            float fn = (red[0] + red[1] + red[2] + red[3]) * (1.f / (3.f * NN));
            stat[0] = vg[c2] * rsqrtf(fn + 1e-5f);
        }
        __syncthreads();
        float scale = stat[0];
        for (int n = t; n < NN; n += 256) {
            for (int x = 0; x < 3; x++) {
                int ix = n * 24 + c2 * 3 + x;
                xv[ix] = (xv[ix] + agv[ix]) * scale;
            }
        }
    }
}

__global__ __launch_bounds__(128)
void final_out(const float* __restrict__ xs, const float* __restrict__ xv,
               const float* __restrict__ rot,
               const float* __restrict__ mu_w, const float* __restrict__ mu_b,
               const float* __restrict__ lv_w, const float* __restrict__ lv_b,
               float* __restrict__ out)
{
    __shared__ float feat[56];
    int n = blockIdx.x, t = threadIdx.x;
    if (t < 32) feat[t] = xs[n * CS + t];
    else if (t < 56) {
        int t2 = t - 32, c = t2 / 3, y = t2 - 3 * (t2 / 3);
        float acc = 0.f;
        for (int x = 0; x < 3; x++)
            acc += rot[n * 9 + x * 3 + y] * xv[n * 24 + c * 3 + x];
        feat[t] = acc;
    }
    __syncthreads();
    float mu = mu_b[t], lv = lv_b[t];
    for (int d = 0; d < 56; d++) {
        float f = feat[d];
        mu += f * mu_w[d * 128 + t];
        lv += f * lv_w[d * 128 + t];
    }
    out[(size_t)n * 128 + t] = mu;
    out[(size_t)NN * 128 + (size_t)n * 128 + t] = lv;
}

// ---------------------------------------------------------------------------
extern "C" void kernel_launch(void* const* d_in, const int* in_sizes, int n_in,
                              void* d_out, int out_size, void* d_ws, size_t ws_size,
                              hipStream_t stream)
{
    (void)in_sizes; (void)n_in; (void)out_size; (void)ws_size;
    const float* node_raw  = (const float*)d_in[0];
    const float* edge_raw  = (const float*)d_in[1];
    const float* edge_vecs = (const float*)d_in[2];
    const float* rot       = (const float*)d_in[3];
    const int*   ei        = (const int*  )d_in[4];
    const float* ee_w1 = (const float*)d_in[5];
    const float* ee_b1 = (const float*)d_in[6];
    const float* ee_w2 = (const float*)d_in[7];
    const float* ee_b2 = (const float*)d_in[8];
    const float* ee_w3 = (const float*)d_in[9];
    const float* ee_b3 = (const float*)d_in[10];
    const float* ee_ln_g = (const float*)d_in[11];
    const float* ee_ln_b = (const float*)d_in[12];
    const float* ne_ws = (const float*)d_in[13];
    const float* ne_wv = (const float*)d_in[14];
    const float* fc_w1 = (const float*)d_in[15];
    const float* fc_b1 = (const float*)d_in[16];
    const float* fc_w2 = (const float*)d_in[17];
    const float* fc_b2 = (const float*)d_in[18];
    const float* bn_g  = (const float*)d_in[19];
    const float* bn_b  = (const float*)d_in[20];
    const float* bn_vg = (const float*)d_in[21];
    const float* eu_lin = (const float*)d_in[22];
    const float* eu_w1 = (const float*)d_in[23];
    const float* eu_b1 = (const float*)d_in[24];
    const float* eu_w2 = (const float*)d_in[25];
    const float* eu_b2 = (const float*)d_in[26];
    const float* eu_w3 = (const float*)d_in[27];
    const float* eu_b3 = (const float*)d_in[28];
    const float* eu_ln_g = (const float*)d_in[29];
    const float* eu_ln_b = (const float*)d_in[30];
    const float* mu_w = (const float*)d_in[31];
    const float* mu_b = (const float*)d_in[32];
    const float* lv_w = (const float*)d_in[33];
    const float* lv_b = (const float*)d_in[34];

    char* ws = (char*)d_ws;
    size_t off = 0;
    auto alloc = [&](size_t bytes) -> void* {
        void* p = ws + off;
        off += (bytes + 255) & ~(size_t)255;
        return p;
    };
    bf16*  ef_b  = (bf16*) alloc((size_t)NE * CZ * 2);     // residual stream
    bf16*  buf_a = (bf16*) alloc((size_t)NE * CZ * 2);     // ee intermediate
    float* xs    = (float*)alloc((size_t)NN * CS * 4);
    float* xv    = (float*)alloc((size_t)NN * 24 * 4);
    float* ags   = (float*)alloc((size_t)NN * CS * 4);
    float* agv   = (float*)alloc((size_t)NN * 24 * 4);
    int*   cnti  = (int*)  alloc((size_t)NN * 4);
    float* icnt  = (float*)alloc((size_t)NN * 4);
    float* adg   = (float*)alloc((size_t)NN * CZ * 4);
    float* asg   = (float*)alloc((size_t)NN * CZ * 4);
    float* Fw    = (float*)alloc((size_t)NL * 2 * CS * CZ * 4);
    float* tp_s  = (float*)alloc((size_t)NE * 32 * 4);
    float* tp_v  = (float*)alloc((size_t)NE * 24 * 4 + 64);
    int*   perm  = (int*)  alloc((size_t)NE * 4);
    int*   row_start = (int*)alloc((size_t)(NN + 1) * 4);
    int*   fillpos   = (int*)alloc((size_t)NN * 4);
    bf16* ee_w1t = (bf16*)alloc((size_t)INZ * CZ * 2);
    bf16* ee_w2t = (bf16*)alloc((size_t)CZ * CZ * 2);
    bf16* ee_w3t = (bf16*)alloc((size_t)CZ * CZ * 2);
    bf16* fc_w1t = (bf16*)alloc((size_t)NL * CZ * CZ * 2);
    bf16* fc_w2t = (bf16*)alloc((size_t)NL * WN * CZ * 2);
    bf16* eu_w1ct = (bf16*)alloc((size_t)NL * CZ * CZ * 2);
    bf16* eu_w2t = (bf16*)alloc((size_t)NL * CZ * CZ * 2);
    bf16* eu_w3t = (bf16*)alloc((size_t)NL * CZ * CZ * 2);

    const int TRN = INZ*CZ + 2*CZ*CZ + NL*CZ*CZ + NL*CZ*WN + NL*384*CZ + 2*NL*CZ*CZ;
    transpose_all<<<(TRN + 255) / 256, 256, 0, stream>>>(
        ee_w1, ee_w2, ee_w3, fc_w1, fc_w2, eu_w1, eu_w2, eu_w3,
        ee_w1t, ee_w2t, ee_w3t, fc_w1t, fc_w2t, eu_w1ct, eu_w2t, eu_w3t);
    fold_f<<<NL * 2, 256, 0, stream>>>(eu_lin, eu_w1, Fw);

    node_embed<<<NN, 64, 0, stream>>>(node_raw, ne_ws, ne_wv, xs, xv);
    hipMemsetAsync(cnti, 0, NN * 4, stream);
    count_src<<<NE / 256, 256, 0, stream>>>(ei, cnti);
    scan_csr<<<1, 1024, 0, stream>>>(cnti, row_start, fillpos, icnt);
    fill_perm<<<NE / 256, 256, 0, stream>>>(ei, fillpos, perm);

    const int GE = NE / 64;   // 480
    // edge embedding: ee1 (K=1664 fp32 A) then fused ee2+ee3+LN
    gemm64<1, 1><<<GE, 256, 0, stream>>>(edge_raw, ee_w1t, ee_b1, buf_a, NE, INZ);
    mlp2<<<GE, 256, 0, stream>>>(buf_a, ee_w2t, ee_b2, ee_w3t, ee_b3, ee_ln_g, ee_ln_b, ef_b);

    for (int l = 0; l < NL; l++) {
        fc2_tp<<<GE, 256, 0, stream>>>(
            ef_b, fc_w1t + (size_t)l * CZ * CZ, fc_b1 + l * CZ,
            fc_w2t + (size_t)l * WN * CZ, fc_b2 + l * WN,
            ei, edge_vecs, xs, xv, tp_s, tp_v);
        aggregate<<<NN, 64, 0, stream>>>(tp_s, tp_v, perm, row_start, icnt, ags, agv);
        bnfused<<<40, 256, 0, stream>>>(xs, xv, ags, agv,
                                        bn_g + l * CS, bn_b + l * CS, bn_vg + l * CV);
        adas<<<NN, 128, 0, stream>>>(xs, Fw + (size_t)(l * 2) * CS * CZ,
                                     Fw + (size_t)(l * 2 + 1) * CS * CZ, adg, asg);
        eu_fused<<<GE, 256, 0, stream>>>(
            ef_b, adg, asg, ei,
            eu_w1ct + (size_t)l * CZ * CZ, eu_b1 + l * CZ,
            eu_w2t + (size_t)l * CZ * CZ, eu_b2 + l * CZ,
            eu_w3t + (size_t)l * CZ * CZ, eu_b3 + l * CZ,
            eu_ln_g + l * CZ, eu_ln_b + l * CZ);
    }

    final_out<<<NN, 128, 0, stream>>>(xs, xv, rot, mu_w, mu_b, lv_w, lv_b, (float*)d_out);
}

// Round 5
// 869.077 us; speedup vs baseline: 1.3884x; 1.0096x over previous
//
#include <hip/hip_runtime.h>
#include <hip/hip_bf16.h>

typedef __hip_bfloat16 bf16;
typedef __attribute__((ext_vector_type(8))) short s16x8;   // 8 bf16 (4 VGPRs) MFMA frag
typedef __attribute__((ext_vector_type(4))) float f32x4;   // MFMA accumulator

#define NN 1024      // nodes
#define NE 30720     // edges
#define CS 32
#define CV 8
#define CZ 128
#define INS 28
#define INV 37
#define NRDIM 139    // 28 + 3*37
#define INZ 1664
#define WN 1664      // WEIGHT_NUMEL
#define NL 4

__device__ __forceinline__ float b2f(bf16 x) { return __bfloat162float(x); }
__device__ __forceinline__ bf16 f2b(float x) { return __float2bfloat16(x); }

// ---------------------------------------------------------------------------
// All weight matrices are stored FRAGMENT-LINEAR: for a [R rows k][C cols n]
// matrix, element (k,n) lives at ((n>>4)*(R/32) + (k>>5))*512 + ((k>>3)&3)*128
// + (n&15)*8 + (k&7).  A wave's MFMA B-fragment load for (nt=n>>4, kk=k>>5)
// is ONE contiguous 1 KB load at base + lane*16.
// ---------------------------------------------------------------------------

// Skinny MFMA GEMM, N=128 fixed (only ee1: K=1664 fp32-A, K%64==0).
// Software-pipelined: A (raw) + B fragments prefetched one k-step ahead.
template<int RELU, int AF32>
__global__ __launch_bounds__(256)
void gemm64(const void* __restrict__ Ap, const bf16* __restrict__ Bf,
            const float* __restrict__ bias, bf16* __restrict__ Cp,
            int M, int K)
{
    __shared__ __align__(16) bf16 la[64 * 40];
    const int bm = blockIdx.x * 64;
    const int tid = threadIdx.x;
    const int lane = tid & 63;
    const int wv = tid >> 6;
    const int lr = tid >> 1;
    const int lc = (tid & 1) * 16;
    const int l15 = lane & 15;
    const int quad = lane >> 4;
    const int K32 = K >> 5;
    f32x4 acc[4][2] = {};
    const bf16*  ga16 = (const bf16*) Ap + (size_t)(bm + lr) * K + lc;
    const float* ga32 = (const float*)Ap + (size_t)(bm + lr) * K + lc;

    auto loadA = [&](float4 (&q)[4], int k0) {
        if (tid < 128) {
            if (AF32) {
                q[0] = *(const float4*)(ga32 + k0);
                q[1] = *(const float4*)(ga32 + k0 + 4);
                q[2] = *(const float4*)(ga32 + k0 + 8);
                q[3] = *(const float4*)(ga32 + k0 + 12);
            } else {
                q[0] = *(const float4*)(ga16 + k0);
                q[1] = *(const float4*)(ga16 + k0 + 8);
            }
        }
    };
    auto storeA = [&](float4 (&q)[4]) {
        if (tid < 128) {
            if (AF32) {
                union { bf16 h[16]; float4 v[2]; } pa;
                const float* f = (const float*)q;
#pragma unroll
                for (int i = 0; i < 16; i++) pa.h[i] = f2b(f[i]);
                *(float4*)&la[lr * 40 + lc]     = pa.v[0];
                *(float4*)&la[lr * 40 + lc + 8] = pa.v[1];
            } else {
                *(float4*)&la[lr * 40 + lc]     = q[0];
                *(float4*)&la[lr * 40 + lc + 8] = q[1];
            }
        }
    };
    auto loadB = [&](s16x8 (&B)[2], int k0) {
#pragma unroll
        for (int ni = 0; ni < 2; ni++)
            B[ni] = *(const s16x8*)(Bf + (size_t)(((wv * 2 + ni) * K32 + (k0 >> 5)) * 512) + lane * 8);
    };
    auto mmac = [&](s16x8 (&B)[2]) {
        s16x8 af[4];
#pragma unroll
        for (int mi = 0; mi < 4; mi++)
            af[mi] = *(const s16x8*)&la[(mi * 16 + l15) * 40 + quad * 8];
#pragma unroll
        for (int mi = 0; mi < 4; mi++)
#pragma unroll
            for (int ni = 0; ni < 2; ni++)
                acc[mi][ni] = __builtin_amdgcn_mfma_f32_16x16x32_bf16(af[mi], B[ni], acc[mi][ni], 0, 0, 0);
    };

    float4 qA[4], qB[4];
    s16x8 bA[2], bB[2];
    loadA(qA, 0); loadB(bA, 0);
#pragma unroll 1
    for (int k0 = 0; k0 < K; k0 += 64) {
        loadA(qB, k0 + 32); loadB(bB, k0 + 32);   // K%64==0 -> always in range
        __syncthreads();
        storeA(qA);
        __syncthreads();
        mmac(bA);
        if (k0 + 64 < K) { loadA(qA, k0 + 64); loadB(bA, k0 + 64); }
        __syncthreads();
        storeA(qB);
        __syncthreads();
        mmac(bB);
    }
#pragma unroll
    for (int ni = 0; ni < 2; ni++) {
        const int col = wv * 32 + ni * 16 + l15;
        const float bv = bias[col];
#pragma unroll
        for (int mi = 0; mi < 4; mi++) {
            const int row0 = bm + mi * 16 + quad * 4;
#pragma unroll
            for (int r = 0; r < 4; r++) {
                float v = acc[mi][ni][r] + bv;
                if (RELU) v = fmaxf(v, 0.f);
                Cp[(size_t)(row0 + r) * CZ + col] = f2b(v);
            }
        }
    }
}

// ---------------------------------------------------------------------------
// ee MLP tail: u2 = relu(A@W2+b2); u3 = u2@W3+b3; LN -> efb (bf16).
// W2/W3 fragments PRELOADED to registers at entry (latency hides under
// A-staging) -> GEMM phases have zero global loads.
// ---------------------------------------------------------------------------
__global__ __launch_bounds__(256)
void mlp2(const bf16* __restrict__ A,
          const bf16* __restrict__ w2f, const float* __restrict__ b2,
          const bf16* __restrict__ w3f, const float* __restrict__ b3,
          const float* __restrict__ g, const float* __restrict__ bb,
          bf16* efb)
{
    __shared__ __align__(16) bf16 s_a[64 * 136];
    __shared__ __align__(16) bf16 s_u[64 * 136];
    __shared__ float s_o[64 * 132];
    const int bm = blockIdx.x * 64;
    const int t = threadIdx.x;
    const int lane = t & 63;
    const int wv = t >> 6;
    const int l15 = lane & 15;
    const int quad = lane >> 4;
    s16x8 w2r[2][4], w3r[2][4];
#pragma unroll
    for (int s = 0; s < 2; s++)
#pragma unroll
        for (int kk = 0; kk < 4; kk++) {
            const size_t o = (size_t)(((wv * 2 + s) * 4 + kk) * 512) + lane * 8;
            w2r[s][kk] = *(const s16x8*)(w2f + o);
            w3r[s][kk] = *(const s16x8*)(w3f + o);
        }
    {   // stage A tile 64x128
        int r = t >> 2, c0 = (t & 3) * 32;
        const float4* s4 = (const float4*)(A + (size_t)(bm + r) * CZ + c0);
        float4* d4 = (float4*)&s_a[r * 136 + c0];
        d4[0] = s4[0]; d4[1] = s4[1]; d4[2] = s4[2]; d4[3] = s4[3];
    }
    __syncthreads();
    s16x8 af[4][4];
#pragma unroll
    for (int mi = 0; mi < 4; mi++)
#pragma unroll
        for (int kk = 0; kk < 4; kk++)
            af[mi][kk] = *(const s16x8*)&s_a[(mi * 16 + l15) * 136 + kk * 32 + quad * 8];
#pragma unroll
    for (int s = 0; s < 2; s++) {
        int n = wv * 32 + s * 16 + l15;
        f32x4 acc[4] = {};
#pragma unroll
        for (int kk = 0; kk < 4; kk++)
#pragma unroll
            for (int mi = 0; mi < 4; mi++)
                acc[mi] = __builtin_amdgcn_mfma_f32_16x16x32_bf16(af[mi][kk], w2r[s][kk], acc[mi], 0, 0, 0);
        float bv = b2[n];
#pragma unroll
        for (int mi = 0; mi < 4; mi++)
#pragma unroll
            for (int r = 0; r < 4; r++)
                s_u[(mi * 16 + quad * 4 + r) * 136 + n] = f2b(fmaxf(acc[mi][r] + bv, 0.f));
    }
    __syncthreads();
#pragma unroll
    for (int mi = 0; mi < 4; mi++)
#pragma unroll
        for (int kk = 0; kk < 4; kk++)
            af[mi][kk] = *(const s16x8*)&s_u[(mi * 16 + l15) * 136 + kk * 32 + quad * 8];
#pragma unroll
    for (int s = 0; s < 2; s++) {
        int n = wv * 32 + s * 16 + l15;
        f32x4 acc[4] = {};
#pragma unroll
        for (int kk = 0; kk < 4; kk++)
#pragma unroll
            for (int mi = 0; mi < 4; mi++)
                acc[mi] = __builtin_amdgcn_mfma_f32_16x16x32_bf16(af[mi][kk], w3r[s][kk], acc[mi], 0, 0, 0);
        float bv = b3[n];
#pragma unroll
        for (int mi = 0; mi < 4; mi++)
#pragma unroll
            for (int r = 0; r < 4; r++)
                s_o[(mi * 16 + quad * 4 + r) * 132 + n] = acc[mi][r] + bv;
    }
    __syncthreads();
    {   // LN per row: 4 lanes per row, 32 cols each
        int row = wv * 16 + (lane >> 2);
        int q = lane & 3;
        int col0 = q * 32;
        size_t gbase = (size_t)(bm + row) * CZ;
        float s = 0.f, s2 = 0.f;
        for (int i = 0; i < 32; i++) {
            float x = s_o[row * 132 + col0 + i];
            s += x; s2 += x * x;
        }
        s  += __shfl_xor(s, 1);  s2 += __shfl_xor(s2, 1);
        s  += __shfl_xor(s, 2);  s2 += __shfl_xor(s2, 2);
        float mean = s * (1.f / 128.f);
        float var  = s2 * (1.f / 128.f) - mean * mean;
        float rstd = rsqrtf(var + 1e-5f);
        for (int i = 0; i < 32; i++) {
            int col = col0 + i;
            float x = s_o[row * 132 + col];
            efb[gbase + col] = f2b((x - mean) * rstd * g[col] + bb[col]);
        }
    }
}

// ---------------------------------------------------------------------------
// Fused EdgeUpdate: u1 = relu(ef@W1c + ad[dst] + as[src] + b1);
// u2 = relu(u1@W2+b2); u3 = u2@W3+b3; efb = LN(ef + u3).
// W1c/W2 fragments preloaded at entry, W3 prefetched during phase A ->
// all three GEMM phases run with zero global loads.
// ---------------------------------------------------------------------------
__global__ __launch_bounds__(256)
void eu_fused(bf16* __restrict__ efb,
              const float* __restrict__ adg, const float* __restrict__ asg,
              const int* __restrict__ ei,
              const bf16* __restrict__ w1cf, const float* __restrict__ b1,
              const bf16* __restrict__ w2f, const float* __restrict__ b2,
              const bf16* __restrict__ w3f, const float* __restrict__ b3,
              const float* __restrict__ g, const float* __restrict__ bb)
{
    __shared__ __align__(16) bf16 s_a[64 * 136];     // ef tile (GEMM A + resid)
    __shared__ __align__(16) bf16 s_u1[64 * 136];
    __shared__ __align__(16) float s_go[64 * 132];   // gather -> u2 -> s_o
    bf16* const s_u2 = (bf16*)s_go;
    const int bm = blockIdx.x * 64;
    const int t = threadIdx.x;
    const int lane = t & 63;
    const int wv = t >> 6;
    const int l15 = lane & 15;
    const int quad = lane >> 4;
    s16x8 w1r[2][4], w2r[2][4];
#pragma unroll
    for (int s = 0; s < 2; s++)
#pragma unroll
        for (int kk = 0; kk < 4; kk++) {
            const size_t o = (size_t)(((wv * 2 + s) * 4 + kk) * 512) + lane * 8;
            w1r[s][kk] = *(const s16x8*)(w1cf + o);
            w2r[s][kk] = *(const s16x8*)(w2f + o);
        }
    {   // stage ef tile + gather g = ad[dst] + as[src]
        int r = t >> 2, c0 = (t & 3) * 32;
        const float4* s4 = (const float4*)(efb + (size_t)(bm + r) * CZ + c0);
        float4* d4 = (float4*)&s_a[r * 136 + c0];
        d4[0] = s4[0]; d4[1] = s4[1]; d4[2] = s4[2]; d4[3] = s4[3];
        int dst = ei[bm + r], src = ei[NE + bm + r];
        const float4* pd = (const float4*)(adg + (size_t)dst * CZ + c0);
        const float4* ps = (const float4*)(asg + (size_t)src * CZ + c0);
        float4* dg = (float4*)&s_go[r * 132 + c0];
#pragma unroll
        for (int k = 0; k < 8; k++) {
            float4 va = pd[k], vb = ps[k];
            dg[k] = make_float4(va.x + vb.x, va.y + vb.y, va.z + vb.z, va.w + vb.w);
        }
    }
    __syncthreads();
    // phase A: u1 = relu(ef@W1c + g + b1)
    s16x8 w3r[2][4];
    {
        s16x8 af[4][4];
#pragma unroll
        for (int mi = 0; mi < 4; mi++)
#pragma unroll
            for (int kk = 0; kk < 4; kk++)
                af[mi][kk] = *(const s16x8*)&s_a[(mi * 16 + l15) * 136 + kk * 32 + quad * 8];
        // prefetch W3 while phase-A MFMAs run
#pragma unroll
        for (int s = 0; s < 2; s++)
#pragma unroll
            for (int kk = 0; kk < 4; kk++)
                w3r[s][kk] = *(const s16x8*)(w3f + (size_t)(((wv * 2 + s) * 4 + kk) * 512) + lane * 8);
#pragma unroll
        for (int s = 0; s < 2; s++) {
            int n = wv * 32 + s * 16 + l15;
            f32x4 acc[4] = {};
#pragma unroll
            for (int kk = 0; kk < 4; kk++)
#pragma unroll
                for (int mi = 0; mi < 4; mi++)
                    acc[mi] = __builtin_amdgcn_mfma_f32_16x16x32_bf16(af[mi][kk], w1r[s][kk], acc[mi], 0, 0, 0);
            float bv = b1[n];
#pragma unroll
            for (int mi = 0; mi < 4; mi++)
#pragma unroll
                for (int r = 0; r < 4; r++) {
                    int e = mi * 16 + quad * 4 + r;
                    s_u1[e * 136 + n] = f2b(fmaxf(acc[mi][r] + bv + s_go[e * 132 + n], 0.f));
                }
        }
    }
    __syncthreads();
    // phase B: u2 = relu(u1@W2 + b2) -> s_u2 (aliases s_go; g is dead)
    {
        s16x8 af[4][4];
#pragma unroll
        for (int mi = 0; mi < 4; mi++)
#pragma unroll
            for (int kk = 0; kk < 4; kk++)
                af[mi][kk] = *(const s16x8*)&s_u1[(mi * 16 + l15) * 136 + kk * 32 + quad * 8];
#pragma unroll
        for (int s = 0; s < 2; s++) {
            int n = wv * 32 + s * 16 + l15;
            f32x4 acc[4] = {};
#pragma unroll
            for (int kk = 0; kk < 4; kk++)
#pragma unroll
                for (int mi = 0; mi < 4; mi++)
                    acc[mi] = __builtin_amdgcn_mfma_f32_16x16x32_bf16(af[mi][kk], w2r[s][kk], acc[mi], 0, 0, 0);
            float bv = b2[n];
#pragma unroll
            for (int mi = 0; mi < 4; mi++)
#pragma unroll
                for (int r = 0; r < 4; r++)
                    s_u2[(mi * 16 + quad * 4 + r) * 136 + n] = f2b(fmaxf(acc[mi][r] + bv, 0.f));
        }
    }
    __syncthreads();
    // phase C: x = u2@W3 + b3 + ef (resid); then overwrite s_go with x (f32)
    {
        s16x8 af[4][4];
#pragma unroll
        for (int mi = 0; mi < 4; mi++)
#pragma unroll
            for (int kk = 0; kk < 4; kk++)
                af[mi][kk] = *(const s16x8*)&s_u2[(mi * 16 + l15) * 136 + kk * 32 + quad * 8];
        __syncthreads();   // all u2 reads done before s_go is overwritten
#pragma unroll
        for (int s = 0; s < 2; s++) {
            int n = wv * 32 + s * 16 + l15;
            f32x4 acc[4] = {};
#pragma unroll
            for (int kk = 0; kk < 4; kk++)
#pragma unroll
                for (int mi = 0; mi < 4; mi++)
                    acc[mi] = __builtin_amdgcn_mfma_f32_16x16x32_bf16(af[mi][kk], w3r[s][kk], acc[mi], 0, 0, 0);
            float bv = b3[n];
#pragma unroll
            for (int mi = 0; mi < 4; mi++)
#pragma unroll
                for (int r = 0; r < 4; r++) {
                    int e = mi * 16 + quad * 4 + r;
                    s_go[e * 132 + n] = acc[mi][r] + bv + b2f(s_a[e * 136 + n]);
                }
        }
    }
    __syncthreads();
    {   // LN per row (resid already folded into x)
        int row = wv * 16 + (lane >> 2);
        int q = lane & 3;
        int col0 = q * 32;
        size_t gbase = (size_t)(bm + row) * CZ;
        float s = 0.f, s2 = 0.f;
        for (int i = 0; i < 32; i++) {
            float x = s_go[row * 132 + col0 + i];
            s += x; s2 += x * x;
        }
        s  += __shfl_xor(s, 1);  s2 += __shfl_xor(s2, 1);
        s  += __shfl_xor(s, 2);  s2 += __shfl_xor(s2, 2);
        float mean = s * (1.f / 128.f);
        float var  = s2 * (1.f / 128.f) - mean * mean;
        float rstd = rsqrtf(var + 1e-5f);
        for (int i = 0; i < 32; i++) {
            int col = col0 + i;
            float x = s_go[row * 132 + col];
            efb[gbase + col] = f2b((x - mean) * rstd * g[col] + bb[col]);
        }
    }
}

// ---------------------------------------------------------------------------
// Fused fc1 + fc2 + tensor product.  Block = 64 edges (grid 480).
// Phase 2 is now SOFTWARE-PIPELINED: W2 fragments for iteration nt+4 are
// issued before the MFMA+TP consume of iteration nt (named bA/bB register
// buffers, 13 unrolled pairs) so the ~300-500cy L2 latency hides under
// ~250cy of compute per iteration (only 2 waves/SIMD are resident -> TLP
// alone cannot cover it; counters showed MfmaUtil/VALU/HBM all <10%).
// ---------------------------------------------------------------------------
__global__ __launch_bounds__(256, 2)
void fc2_tp(const bf16* __restrict__ ef,
            const bf16* __restrict__ w1f, const float* __restrict__ b1,
            const bf16* __restrict__ w2f, const float* __restrict__ b2,
            const int* __restrict__ ei, const float* __restrict__ edge_vecs,
            const float* __restrict__ xs, const float* __restrict__ xv,
            float* __restrict__ tp_s, float* __restrict__ tp_v)
{
    __shared__ __align__(16) bf16 s_a[64 * 136];
    __shared__ __align__(16) bf16 s_h[64 * 136];
    __shared__ __align__(16) float s_xsT[32][64];
    __shared__ __align__(16) float s_xvT[24][64];
    __shared__ __align__(16) float s_crT[24][64];
    __shared__ __align__(16) float s_y4T[8][64];
    __shared__ __align__(16) float s_b2[WN];
    __shared__ float s_shv[64][3];
    __shared__ int s_dst[64];
    __shared__ float s_os[64][32];
    __shared__ float s_ov[64][24];
    const int be = blockIdx.x * 64;
    const int t = threadIdx.x;
    const int lane = t & 63;
    const int wv = t >> 6;
    const int l15 = lane & 15;
    const int quad = lane >> 4;
    const int q4 = quad * 4;

    if (t < 64) {
        int e = be + t;
        s_dst[t] = ei[e];
        float vx = edge_vecs[e * 3 + 0];
        float vy = edge_vecs[e * 3 + 1];
        float vz = edge_vecs[e * 3 + 2];
        float sc = 1.7320508075688772f / (sqrtf(vx * vx + vy * vy + vz * vz) + 1e-8f);
        s_shv[t][0] = vx * sc; s_shv[t][1] = vy * sc; s_shv[t][2] = vz * sc;
    }
    for (int i = t; i < 64 * 32; i += 256) ((float*)s_os)[i] = 0.f;
    for (int i = t; i < 64 * 24; i += 256) ((float*)s_ov)[i] = 0.f;
    for (int i = t; i < WN; i += 256) s_b2[i] = b2[i];
    {   // stage ef tile 64x128
        int r = t >> 2, c0 = (t & 3) * 32;
        const float4* s4 = (const float4*)(ef + (size_t)(be + r) * CZ + c0);
        float4* d4 = (float4*)&s_a[r * 136 + c0];
        d4[0] = s4[0]; d4[1] = s4[1]; d4[2] = s4[2]; d4[3] = s4[3];
    }
    __syncthreads();
    for (int i = t; i < 64 * 32; i += 256) { int e = i & 63, c = i >> 6; s_xsT[c][e] = xs[s_dst[e] * CS + c]; }
    for (int i = t; i < 64 * 24; i += 256) { int e = i & 63, c = i >> 6; s_xvT[c][e] = xv[s_dst[e] * 24 + c]; }
    __syncthreads();
    for (int i2 = t; i2 < 512; i2 += 256) {
        int e = i2 & 63, i = i2 >> 6;
        float h0 = s_shv[e][0], h1 = s_shv[e][1], h2 = s_shv[e][2];
        float x0 = s_xvT[i * 3 + 0][e], x1 = s_xvT[i * 3 + 1][e], x2 = s_xvT[i * 3 + 2][e];
        s_y4T[i][e] = 1.1547005383792515f * (x0 * h0 + x1 * h1 + x2 * h2);
        s_crT[i * 3 + 0][e] = 0.7071067811865476f * (x1 * h2 - x2 * h1);
        s_crT[i * 3 + 1][e] = 0.7071067811865476f * (x2 * h0 - x0 * h2);
        s_crT[i * 3 + 2][e] = 0.7071067811865476f * (x0 * h1 - x1 * h0);
    }
    // phase 1: h = relu(ef@W1+b1)
    {
        s16x8 af1[4][4];
#pragma unroll
        for (int mi = 0; mi < 4; mi++)
#pragma unroll
            for (int kk = 0; kk < 4; kk++)
                af1[mi][kk] = *(const s16x8*)&s_a[(mi * 16 + l15) * 136 + kk * 32 + quad * 8];
#pragma unroll
        for (int s = 0; s < 2; s++) {
            int n = wv * 32 + s * 16 + l15;
            f32x4 acc[4] = {};
#pragma unroll
            for (int kk = 0; kk < 4; kk++) {
                s16x8 bfr = *(const s16x8*)(w1f + (size_t)(((wv * 2 + s) * 4 + kk) * 512) + lane * 8);
#pragma unroll
                for (int mi = 0; mi < 4; mi++)
                    acc[mi] = __builtin_amdgcn_mfma_f32_16x16x32_bf16(af1[mi][kk], bfr, acc[mi], 0, 0, 0);
            }
            float bv = b1[n];
#pragma unroll
            for (int mi = 0; mi < 4; mi++)
#pragma unroll
                for (int r = 0; r < 4; r++)
                    s_h[(mi * 16 + quad * 4 + r) * 136 + n] = f2b(fmaxf(acc[mi][r] + bv, 0.f));
        }
    }
    __syncthreads();
    // phase 2: stream w = h@W2+b2 through registers, contract immediately,
    // double-buffered W2 prefetch.
    s16x8 af[4][4];
#pragma unroll
    for (int mi = 0; mi < 4; mi++)
#pragma unroll
        for (int kk = 0; kk < 4; kk++)
            af[mi][kk] = *(const s16x8*)&s_h[(mi * 16 + l15) * 136 + kk * 32 + quad * 8];
    float os[4][4] = {}, sv2[4][4] = {}, ov0[4][4] = {}, ov1[4][4] = {}, ov2[4][4] = {};
    const int ib = l15 >> 3;

    auto loadw = [&](s16x8 (&B)[4], int NT) {
        const bf16* wb = w2f + (size_t)(NT * 4) * 512 + lane * 8;
#pragma unroll
        for (int kk = 0; kk < 4; kk++) B[kk] = *(const s16x8*)(wb + kk * 512);
    };
    auto consume = [&](int nt, s16x8 (&bfr)[4]) {
        const float bv = s_b2[nt * 16 + l15];
        f32x4 ac[4] = {};
#pragma unroll
        for (int kk = 0; kk < 4; kk++)
#pragma unroll
            for (int mi = 0; mi < 4; mi++)
                ac[mi] = __builtin_amdgcn_mfma_f32_16x16x32_bf16(af[mi][kk], bfr[kk], ac[mi], 0, 0, 0);
        if (nt < 64) {
            const int i = nt >> 1;
#pragma unroll
            for (int mi = 0; mi < 4; mi++) {
                float4 f = *(const float4*)&s_xsT[i][mi * 16 + q4];
                os[mi][0] += (ac[mi][0] + bv) * f.x; os[mi][1] += (ac[mi][1] + bv) * f.y;
                os[mi][2] += (ac[mi][2] + bv) * f.z; os[mi][3] += (ac[mi][3] + bv) * f.w;
            }
        } else if (nt < 80) {
            const int i = (nt - 64) * 2 + ib;
#pragma unroll
            for (int mi = 0; mi < 4; mi++) {
                float4 f = *(const float4*)&s_xsT[i][mi * 16 + q4];
                sv2[mi][0] += (ac[mi][0] + bv) * f.x; sv2[mi][1] += (ac[mi][1] + bv) * f.y;
                sv2[mi][2] += (ac[mi][2] + bv) * f.z; sv2[mi][3] += (ac[mi][3] + bv) * f.w;
            }
        } else if (nt < 84) {
            const int i0 = ((nt - 80) * 2 + ib) * 3;
#pragma unroll
            for (int mi = 0; mi < 4; mi++) {
                float4 f0 = *(const float4*)&s_xvT[i0 + 0][mi * 16 + q4];
                float4 f1 = *(const float4*)&s_xvT[i0 + 1][mi * 16 + q4];
                float4 f2 = *(const float4*)&s_xvT[i0 + 2][mi * 16 + q4];
                float w0 = ac[mi][0] + bv, w1 = ac[mi][1] + bv, w2 = ac[mi][2] + bv, w3 = ac[mi][3] + bv;
                ov0[mi][0] += w0 * f0.x; ov0[mi][1] += w1 * f0.y; ov0[mi][2] += w2 * f0.z; ov0[mi][3] += w3 * f0.w;
                ov1[mi][0] += w0 * f1.x; ov1[mi][1] += w1 * f1.y; ov1[mi][2] += w2 * f1.z; ov1[mi][3] += w3 * f1.w;
                ov2[mi][0] += w0 * f2.x; ov2[mi][1] += w1 * f2.y; ov2[mi][2] += w2 * f2.z; ov2[mi][3] += w3 * f2.w;
            }
        } else if (nt < 100) {
            const int i = (nt - 84) >> 1;
#pragma unroll
            for (int mi = 0; mi < 4; mi++) {
                float4 f = *(const float4*)&s_y4T[i][mi * 16 + q4];
                os[mi][0] += (ac[mi][0] + bv) * f.x; os[mi][1] += (ac[mi][1] + bv) * f.y;
                os[mi][2] += (ac[mi][2] + bv) * f.z; os[mi][3] += (ac[mi][3] + bv) * f.w;
            }
        } else {
            const int i0 = ((nt - 100) * 2 + ib) * 3;
#pragma unroll
            for (int mi = 0; mi < 4; mi++) {
                float4 f0 = *(const float4*)&s_crT[i0 + 0][mi * 16 + q4];
                float4 f1 = *(const float4*)&s_crT[i0 + 1][mi * 16 + q4];
                float4 f2 = *(const float4*)&s_crT[i0 + 2][mi * 16 + q4];
                float w0 = ac[mi][0] + bv, w1 = ac[mi][1] + bv, w2 = ac[mi][2] + bv, w3 = ac[mi][3] + bv;
                ov0[mi][0] += w0 * f0.x; ov0[mi][1] += w1 * f0.y; ov0[mi][2] += w2 * f0.z; ov0[mi][3] += w3 * f0.w;
                ov1[mi][0] += w0 * f1.x; ov1[mi][1] += w1 * f1.y; ov1[mi][2] += w2 * f1.z; ov1[mi][3] += w3 * f1.w;
                ov2[mi][0] += w0 * f2.x; ov2[mi][1] += w1 * f2.y; ov2[mi][2] += w2 * f2.z; ov2[mi][3] += w3 * f2.w;
            }
        }
    };

    {
        s16x8 bA[4], bB[4];
        int nt = wv;                 // 26 iterations: nt = wv + 4*{0..25}
        loadw(bA, nt);
#pragma unroll 1
        for (int p = 0; p < 13; p++) {
            loadw(bB, nt + 4);       // max wv+100 <= 103, always valid
            consume(nt, bA);
            if (p < 12) loadw(bA, nt + 8);
            consume(nt + 4, bB);
            nt += 8;
        }
    }
    {
        const int jo = (wv & 1) * 16 + l15;
        const int jv3 = (l15 & 7) * 3;
#pragma unroll
        for (int mi = 0; mi < 4; mi++)
#pragma unroll
            for (int r = 0; r < 4; r++) {
                int e = mi * 16 + quad * 4 + r;
                atomicAdd(&s_os[e][jo], os[mi][r]);
                float sv = 0.5f * sv2[mi][r];
                atomicAdd(&s_ov[e][jv3 + 0], ov0[mi][r] + s_shv[e][0] * sv);
                atomicAdd(&s_ov[e][jv3 + 1], ov1[mi][r] + s_shv[e][1] * sv);
                atomicAdd(&s_ov[e][jv3 + 2], ov2[mi][r] + s_shv[e][2] * sv);
            }
    }
    __syncthreads();
    for (int i = t; i < 64 * 32; i += 256) {
        int e = i >> 5, d = i & 31;
        tp_s[(size_t)(be + e) * 32 + d] = s_os[e][d] * 0.125f;
    }
    for (int i = t; i < 64 * 24; i += 256) {
        int e = i / 24, d = i - e * 24;
        tp_v[(size_t)(be + e) * 24 + d] = s_ov[e][d] * 0.2041241452319315f;
    }
}

// ---------------------------------------------------------------------------
// CSR build + segment-sum gather (unchanged).
// ---------------------------------------------------------------------------
__global__ __launch_bounds__(1024)
void scan_csr(const int* __restrict__ cnt, int* __restrict__ row_start,
              int* __restrict__ fillpos, float* __restrict__ icnt)
{
    __shared__ int tmp[1024];
    int t = threadIdx.x;
    int v = cnt[t];
    tmp[t] = v;
    __syncthreads();
    for (int o = 1; o < 1024; o <<= 1) {
        int x = (t >= o) ? tmp[t - o] : 0;
        __syncthreads();
        tmp[t] += x;
        __syncthreads();
    }
    int excl = tmp[t] - v;
    row_start[t] = excl;
    fillpos[t] = excl;
    if (t == 1023) row_start[1024] = tmp[1023];
    icnt[t] = 1.0f / (float)(v > 1 ? v : 1);
}

__global__ void fill_perm(const int* __restrict__ ei, int* __restrict__ fillpos,
                          int* __restrict__ perm)
{
    int e = blockIdx.x * 256 + threadIdx.x;
    if (e < NE) {
        int s = ei[NE + e];
        int p = atomicAdd(&fillpos[s], 1);
        perm[p] = e;
    }
}

__global__ __launch_bounds__(64)
void aggregate(const float* __restrict__ tp_s, const float* __restrict__ tp_v,
               const int* __restrict__ perm, const int* __restrict__ row_start,
               const float* __restrict__ icnt,
               float* __restrict__ ags, float* __restrict__ agv)
{
    __shared__ int s_e[64];
    const int n = blockIdx.x, t = threadIdx.x;
    const int s = row_start[n], epe = row_start[n + 1];
    float acc = 0.f;
    for (int k0 = s; k0 < epe; k0 += 64) {
        int kk = k0 + t;
        s_e[t] = (kk < epe) ? perm[kk] : 0;
        __syncthreads();
        int m = epe - k0; if (m > 64) m = 64;
        for (int j = 0; j < m; j++) {
            int e = s_e[j];
            acc += (t < 32) ? tp_s[(size_t)e * 32 + t]
                            : tp_v[(size_t)e * 24 + (t - 32)];
        }
        __syncthreads();
    }
    acc *= icnt[n];
    if (t < 32) ags[n * CS + t] = acc;
    else if (t < 56) agv[n * 24 + (t - 32)] = acc;
}

// ---------------------------------------------------------------------------
// Weight repack: fragment-linear for a [R][C] matrix (leading layer dim l).
// eu_w1: only rows 256..383 (the ef part) are repacked — rows 0..255 are
// folded into per-node ad/as via fold_f.
// ---------------------------------------------------------------------------
__device__ __forceinline__ void fragseg(int i, int R, int C,
                                        const float* __restrict__ s, bf16* __restrict__ d)
{
    int l = i / (R * C);
    int rem = i - l * R * C;
    int k = rem / C;
    int n = rem - k * C;
    int dst = ((n >> 4) * (R >> 5) + (k >> 5)) * 512 + ((k >> 3) & 3) * 128 + (n & 15) * 8 + (k & 7);
    d[(size_t)l * R * C + dst] = f2b(s[i]);
}

__global__ void transpose_all(const float* __restrict__ p0, const float* __restrict__ p1,
                              const float* __restrict__ p2, const float* __restrict__ p3,
                              const float* __restrict__ p4, const float* __restrict__ p5,
                              const float* __restrict__ p6, const float* __restrict__ p7,
                              bf16* d0, bf16* d1, bf16* d2, bf16* d3,
                              bf16* d4, bf16* d5, bf16* d6, bf16* d7)
{
    int i = blockIdx.x * 256 + threadIdx.x;
    const int S0 = INZ * CZ;            // ee_w1  (R=1664,C=128)
    const int S1 = CZ * CZ;             // ee_w2
    const int S2 = CZ * CZ;             // ee_w3
    const int S3 = NL * CZ * CZ;        // fc_w1
    const int S4 = NL * CZ * WN;        // fc_w2  (R=128,C=1664)
    const int S5 = NL * 384 * CZ;       // eu_w1  (only k>=256 repacked)
    const int S6 = NL * CZ * CZ;        // eu_w2
    const int S7 = NL * CZ * CZ;        // eu_w3
    if (i < S0) { fragseg(i, INZ, CZ, p0, d0); return; } i -= S0;
    if (i < S1) { fragseg(i, CZ, CZ, p1, d1); return; }  i -= S1;
    if (i < S2) { fragseg(i, CZ, CZ, p2, d2); return; }  i -= S2;
    if (i < S3) { fragseg(i, CZ, CZ, p3, d3); return; }  i -= S3;
    if (i < S4) { fragseg(i, CZ, WN, p4, d4); return; }  i -= S4;
    if (i < S5) {
        int l = i / (384 * CZ);
        int rem = i - l * (384 * CZ);
        int k = rem / CZ, n = rem - k * CZ;
        if (k >= 256) {
            int k2 = k - 256;
            int dst = ((n >> 4) * (CZ >> 5) + (k2 >> 5)) * 512 + ((k2 >> 3) & 3) * 128 + (n & 15) * 8 + (k2 & 7);
            d5[(size_t)l * CZ * CZ + dst] = f2b(p5[i]);
        }
        return;
    } i -= S5;
    if (i < S6) { fragseg(i, CZ, CZ, p6, d6); return; }  i -= S6;
    if (i < S7) { fragseg(i, CZ, CZ, p7, d7); return; }
}

// F_d = eu_lin @ W1a, F_s = eu_lin @ W1b  (per layer, f32).  8 blocks.
__global__ __launch_bounds__(256)
void fold_f(const float* __restrict__ eu_lin, const float* __restrict__ eu_w1,
            float* __restrict__ Fw)
{
    int b = blockIdx.x, t = threadIdx.x;
    int l = b >> 1, part = b & 1;
    const float* L = eu_lin + (size_t)l * CS * CZ;
    const float* W = eu_w1 + (size_t)l * 384 * CZ + (size_t)part * CZ * CZ;
    float* out = Fw + (size_t)b * CS * CZ;
    for (int idx = t; idx < CS * CZ; idx += 256) {
        int i = idx >> 7, n = idx & 127;
        float acc = 0.f;
        for (int k = 0; k < CZ; k++)
            acc += L[i * CZ + k] * W[k * CZ + n];
        out[idx] = acc;
    }
}

// ad = xs@F_d, as = xs@F_s  (f32 out)
__global__ __launch_bounds__(128)
void adas(const float* __restrict__ xs, const float* __restrict__ Fd,
          const float* __restrict__ Fs, float* __restrict__ adg, float* __restrict__ asg)
{
    __shared__ float sxs[32];
    int n = blockIdx.x, t = threadIdx.x;
    if (t < 32) sxs[t] = xs[n * CS + t];
    __syncthreads();
    float a = 0.f, b = 0.f;
    for (int i = 0; i < 32; i++) {
        float x = sxs[i];
        a += x * Fd[i * CZ + t];
        b += x * Fs[i * CZ + t];
    }
    adg[(size_t)n * CZ + t] = a;
    asg[(size_t)n * CZ + t] = b;
}

__global__ __launch_bounds__(64)
void node_embed(const float* __restrict__ node_raw, const float* __restrict__ ne_ws,
                const float* __restrict__ ne_wv, float* __restrict__ xs, float* __restrict__ xv)
{
    int n = blockIdx.x, t = threadIdx.x;
    const float* nr = node_raw + (size_t)n * NRDIM;
    if (t < 32) {
        float acc = 0.f;
        for (int i = 0; i < INS; i++) acc += nr[i] * ne_ws[i * CS + t];
        xs[n * CS + t] = acc;
    } else if (t < 56) {
        int t2 = t - 32, j = t2 / 3, x = t2 - 3 * (t2 / 3);
        float acc = 0.f;
        for (int i = 0; i < INV; i++) acc += nr[INS + i * 3 + x] * ne_wv[i * CV + j];
        xv[n * 24 + t2] = acc;
    }
}

__global__ void count_src(const int* __restrict__ ei, int* __restrict__ cnt)
{
    int e = blockIdx.x * 256 + threadIdx.x;
    if (e < NE) atomicAdd(&cnt[ei[NE + e]], 1);
}

// add agg + batchnorm stats + apply.  40 blocks.
__global__ __launch_bounds__(256)
void bnfused(float* __restrict__ xs, float* __restrict__ xv,
             const float* __restrict__ ags, const float* __restrict__ agv,
             const float* __restrict__ g, const float* __restrict__ b,
             const float* __restrict__ vg)
{
    __shared__ float red[8];
    __shared__ float stat[2];
    int c = blockIdx.x, t = threadIdx.x;
    if (c < 32) {
        float s = 0.f, s2 = 0.f;
        for (int n = t; n < NN; n += 256) {
            float v = xs[n * CS + c] + ags[n * CS + c];
            s += v; s2 += v * v;
        }
        for (int o = 32; o > 0; o >>= 1) { s += __shfl_down(s, o); s2 += __shfl_down(s2, o); }
        int w = t >> 6;
        if ((t & 63) == 0) { red[w * 2] = s; red[w * 2 + 1] = s2; }
        __syncthreads();
        if (t == 0) {
            float S = red[0] + red[2] + red[4] + red[6];
            float S2 = red[1] + red[3] + red[5] + red[7];
            float mean = S * (1.f / NN);
            float var = S2 * (1.f / NN) - mean * mean;
            stat[0] = mean;
            stat[1] = rsqrtf(var + 1e-5f);
        }
        __syncthreads();
        float mean = stat[0], rstd = stat[1], gg = g[c], bb = b[c];
        for (int n = t; n < NN; n += 256) {
            int ix = n * CS + c;
            float v = xs[ix] + ags[ix];
            xs[ix] = (v - mean) * rstd * gg + bb;
        }
    } else {
        int c2 = c - 32;
        float s = 0.f;
        for (int n = t; n < NN; n += 256) {
            float v0 = xv[n * 24 + c2 * 3 + 0] + agv[n * 24 + c2 * 3 + 0];
            float v1 = xv[n * 24 + c2 * 3 + 1] + agv[n * 24 + c2 * 3 + 1];
            float v2 = xv[n * 24 + c2 * 3 + 2] + agv[n * 24 + c2 * 3 + 2];
            s += v0 * v0 + v1 * v1 + v2 * v2;
        }
        for (int o = 32; o > 0; o >>= 1) s += __shfl_down(s, o);
        int w = t >> 6;
        if ((t & 63) == 0) red[w] = s;
        __syncthreads();
        if (t == 0) {
            float fn = (red[0] + red[1] + red[2] + red[3]) * (1.f / (3.f * NN));
            stat[0] = vg[c2] * rsqrtf(fn + 1e-5f);
        }
        __syncthreads();
        float scale = stat[0];
        for (int n = t; n < NN; n += 256) {
            for (int x = 0; x < 3; x++) {
                int ix = n * 24 + c2 * 3 + x;
                xv[ix] = (xv[ix] + agv[ix]) * scale;
            }
        }
    }
}

__global__ __launch_bounds__(128)
void final_out(const float* __restrict__ xs, const float* __restrict__ xv,
               const float* __restrict__ rot,
               const float* __restrict__ mu_w, const float* __restrict__ mu_b,
               const float* __restrict__ lv_w, const float* __restrict__ lv_b,
               float* __restrict__ out)
{
    __shared__ float feat[56];
    int n = blockIdx.x, t = threadIdx.x;
    if (t < 32) feat[t] = xs[n * CS + t];
    else if (t < 56) {
        int t2 = t - 32, c = t2 / 3, y = t2 - 3 * (t2 / 3);
        float acc = 0.f;
        for (int x = 0; x < 3; x++)
            acc += rot[n * 9 + x * 3 + y] * xv[n * 24 + c * 3 + x];
        feat[t] = acc;
    }
    __syncthreads();
    float mu = mu_b[t], lv = lv_b[t];
    for (int d = 0; d < 56; d++) {
        float f = feat[d];
        mu += f * mu_w[d * 128 + t];
        lv += f * lv_w[d * 128 + t];
    }
    out[(size_t)n * 128 + t] = mu;
    out[(size_t)NN * 128 + (size_t)n * 128 + t] = lv;
}

// ---------------------------------------------------------------------------
extern "C" void kernel_launch(void* const* d_in, const int* in_sizes, int n_in,
                              void* d_out, int out_size, void* d_ws, size_t ws_size,
                              hipStream_t stream)
{
    (void)in_sizes; (void)n_in; (void)out_size; (void)ws_size;
    const float* node_raw  = (const float*)d_in[0];
    const float* edge_raw  = (const float*)d_in[1];
    const float* edge_vecs = (const float*)d_in[2];
    const float* rot       = (const float*)d_in[3];
    const int*   ei        = (const int*  )d_in[4];
    const float* ee_w1 = (const float*)d_in[5];
    const float* ee_b1 = (const float*)d_in[6];
    const float* ee_w2 = (const float*)d_in[7];
    const float* ee_b2 = (const float*)d_in[8];
    const float* ee_w3 = (const float*)d_in[9];
    const float* ee_b3 = (const float*)d_in[10];
    const float* ee_ln_g = (const float*)d_in[11];
    const float* ee_ln_b = (const float*)d_in[12];
    const float* ne_ws = (const float*)d_in[13];
    const float* ne_wv = (const float*)d_in[14];
    const float* fc_w1 = (const float*)d_in[15];
    const float* fc_b1 = (const float*)d_in[16];
    const float* fc_w2 = (const float*)d_in[17];
    const float* fc_b2 = (const float*)d_in[18];
    const float* bn_g  = (const float*)d_in[19];
    const float* bn_b  = (const float*)d_in[20];
    const float* bn_vg = (const float*)d_in[21];
    const float* eu_lin = (const float*)d_in[22];
    const float* eu_w1 = (const float*)d_in[23];
    const float* eu_b1 = (const float*)d_in[24];
    const float* eu_w2 = (const float*)d_in[25];
    const float* eu_b2 = (const float*)d_in[26];
    const float* eu_w3 = (const float*)d_in[27];
    const float* eu_b3 = (const float*)d_in[28];
    const float* eu_ln_g = (const float*)d_in[29];
    const float* eu_ln_b = (const float*)d_in[30];
    const float* mu_w = (const float*)d_in[31];
    const float* mu_b = (const float*)d_in[32];
    const float* lv_w = (const float*)d_in[33];
    const float* lv_b = (const float*)d_in[34];

    char* ws = (char*)d_ws;
    size_t off = 0;
    auto alloc = [&](size_t bytes) -> void* {
        void* p = ws + off;
        off += (bytes + 255) & ~(size_t)255;
        return p;
    };
    bf16*  ef_b  = (bf16*) alloc((size_t)NE * CZ * 2);     // residual stream
    bf16*  buf_a = (bf16*) alloc((size_t)NE * CZ * 2);     // ee intermediate
    float* xs    = (float*)alloc((size_t)NN * CS * 4);
    float* xv    = (float*)alloc((size_t)NN * 24 * 4);
    float* ags   = (float*)alloc((size_t)NN * CS * 4);
    float* agv   = (float*)alloc((size_t)NN * 24 * 4);
    int*   cnti  = (int*)  alloc((size_t)NN * 4);
    float* icnt  = (float*)alloc((size_t)NN * 4);
    float* adg   = (float*)alloc((size_t)NN * CZ * 4);
    float* asg   = (float*)alloc((size_t)NN * CZ * 4);
    float* Fw    = (float*)alloc((size_t)NL * 2 * CS * CZ * 4);
    float* tp_s  = (float*)alloc((size_t)NE * 32 * 4);
    float* tp_v  = (float*)alloc((size_t)NE * 24 * 4 + 64);
    int*   perm  = (int*)  alloc((size_t)NE * 4);
    int*   row_start = (int*)alloc((size_t)(NN + 1) * 4);
    int*   fillpos   = (int*)alloc((size_t)NN * 4);
    bf16* ee_w1t = (bf16*)alloc((size_t)INZ * CZ * 2);
    bf16* ee_w2t = (bf16*)alloc((size_t)CZ * CZ * 2);
    bf16* ee_w3t = (bf16*)alloc((size_t)CZ * CZ * 2);
    bf16* fc_w1t = (bf16*)alloc((size_t)NL * CZ * CZ * 2);
    bf16* fc_w2t = (bf16*)alloc((size_t)NL * WN * CZ * 2);
    bf16* eu_w1ct = (bf16*)alloc((size_t)NL * CZ * CZ * 2);
    bf16* eu_w2t = (bf16*)alloc((size_t)NL * CZ * CZ * 2);
    bf16* eu_w3t = (bf16*)alloc((size_t)NL * CZ * CZ * 2);

    const int TRN = INZ*CZ + 2*CZ*CZ + NL*CZ*CZ + NL*CZ*WN + NL*384*CZ + 2*NL*CZ*CZ;
    transpose_all<<<(TRN + 255) / 256, 256, 0, stream>>>(
        ee_w1, ee_w2, ee_w3, fc_w1, fc_w2, eu_w1, eu_w2, eu_w3,
        ee_w1t, ee_w2t, ee_w3t, fc_w1t, fc_w2t, eu_w1ct, eu_w2t, eu_w3t);
    fold_f<<<NL * 2, 256, 0, stream>>>(eu_lin, eu_w1, Fw);

    node_embed<<<NN, 64, 0, stream>>>(node_raw, ne_ws, ne_wv, xs, xv);
    hipMemsetAsync(cnti, 0, NN * 4, stream);
    count_src<<<NE / 256, 256, 0, stream>>>(ei, cnti);
    scan_csr<<<1, 1024, 0, stream>>>(cnti, row_start, fillpos, icnt);
    fill_perm<<<NE / 256, 256, 0, stream>>>(ei, fillpos, perm);

    const int GE = NE / 64;   // 480
    // edge embedding: ee1 (K=1664 fp32 A) then fused ee2+ee3+LN
    gemm64<1, 1><<<GE, 256, 0, stream>>>(edge_raw, ee_w1t, ee_b1, buf_a, NE, INZ);
    mlp2<<<GE, 256, 0, stream>>>(buf_a, ee_w2t, ee_b2, ee_w3t, ee_b3, ee_ln_g, ee_ln_b, ef_b);

    for (int l = 0; l < NL; l++) {
        fc2_tp<<<GE, 256, 0, stream>>>(
            ef_b, fc_w1t + (size_t)l * CZ * CZ, fc_b1 + l * CZ,
            fc_w2t + (size_t)l * WN * CZ, fc_b2 + l * WN,
            ei, edge_vecs, xs, xv, tp_s, tp_v);
        aggregate<<<NN, 64, 0, stream>>>(tp_s, tp_v, perm, row_start, icnt, ags, agv);
        bnfused<<<40, 256, 0, stream>>>(xs, xv, ags, agv,
                                        bn_g + l * CS, bn_b + l * CS, bn_vg + l * CV);
        adas<<<NN, 128, 0, stream>>>(xs, Fw + (size_t)(l * 2) * CS * CZ,
                                     Fw + (size_t)(l * 2 + 1) * CS * CZ, adg, asg);
        eu_fused<<<GE, 256, 0, stream>>>(
            ef_b, adg, asg, ei,
            eu_w1ct + (size_t)l * CZ * CZ, eu_b1 + l * CZ,
            eu_w2t + (size_t)l * CZ * CZ, eu_b2 + l * CZ,
            eu_w3t + (size_t)l * CZ * CZ, eu_b3 + l * CZ,
            eu_ln_g + l * CZ, eu_ln_b + l * CZ);
    }

    final_out<<<NN, 128, 0, stream>>>(xs, xv, rot, mu_w, mu_b, lv_w, lv_b, (float*)d_out);
}